// Round 1
// 373.289 us; speedup vs baseline: 1.0058x; 1.0058x over previous
//
#include <hip/hip_runtime.h>
#include <stdint.h>

// MultiHeadAttention: B=2, S=2048, D=2048, H=16, Dh=128, fp32 in/out.
// R6: gemm_qkv rewritten as 256x256-tile / 8-wave / 8-phase pipelined GEMM
//     (HK-m201 style): 128 KiB double-buffered LDS, raw s_barrier (no vmcnt
//     drain in the K-loop), counted s_waitcnt vmcnt(4) twice per 2-K-tile
//     iteration, setprio(1) around each 16-MFMA cluster, XCD-aware bijective
//     block swizzle. Epilogues (fused RoPE for Q/K, transposed copy-out for
//     V) kept, widened to the 256-wide tile (LDS reused as 256x256 bf16).
//     attn_kernel / gemm_out / conv_all unchanged from R5.

#define SEQ 2048
#define HD 128
#define DMODEL 2048

typedef __bf16 bf16x8 __attribute__((ext_vector_type(8)));
typedef float f32x4 __attribute__((ext_vector_type(4)));
typedef unsigned short u16;
typedef unsigned int u32;

typedef bf16x8 __attribute__((may_alias)) bf16x8_a;
typedef uint2 __attribute__((may_alias)) uint2_a;
typedef uint4 __attribute__((may_alias)) uint4_a;

__device__ __forceinline__ u16 f2bf(float f) {
  unsigned int u = __float_as_uint(f);
  u += 0x7fff + ((u >> 16) & 1);   // RNE; inputs are finite normals
  return (u16)(u >> 16);
}

typedef __attribute__((address_space(1))) void* gas_t;
typedef __attribute__((address_space(3))) void* las_t;
// async global->LDS, 16B/lane. LDS dest must be uniform base + lane*16.
__device__ __forceinline__ void load_lds16(const void* g, void* l) {
  __builtin_amdgcn_global_load_lds((gas_t)(uintptr_t)g,
                                   (las_t)(uint32_t)(uintptr_t)l, 16, 0, 0);
}

// ---------------- fp32 -> bf16 convert (all 5 tensors, one launch) ---------
__global__ void conv_all(const float* __restrict__ x,
                         const float* __restrict__ wq,
                         const float* __restrict__ wk,
                         const float* __restrict__ wv,
                         const float* __restrict__ wo,
                         u16* __restrict__ xb, u16* __restrict__ wqkv,
                         u16* __restrict__ wob) {
  int i = blockIdx.x * 256 + threadIdx.x;  // float4 index
  const float* src;
  u16* dst;
  int off;
  if (i < 2097152) { src = x; dst = xb; off = i; }
  else if (i < 3145728) { src = wq; dst = wqkv; off = i - 2097152; }
  else if (i < 4194304) { src = wk; dst = wqkv + 4194304; off = i - 3145728; }
  else if (i < 5242880) { src = wv; dst = wqkv + 8388608; off = i - 4194304; }
  else { src = wo; dst = wob; off = i - 5242880; }
  float4 v = ((const float4*)src)[off];
  ushort4 o;
  o.x = f2bf(v.x); o.y = f2bf(v.y); o.z = f2bf(v.z); o.w = f2bf(v.w);
  ((ushort4*)dst)[off] = o;
}

// ---------------- shared 128x128 GEMM core (kept for gemm_out) -------------
template <bool SWAP>
__device__ __forceinline__ void gemm_core(
    const u16* __restrict__ A, const u16* __restrict__ Bm, int row0, int col0,
    int K, u16* Asl, u16* Bsl, int wave, int lane, int quad, int l15,
    int waveM, int waveN, f32x4 acc[4][4]) {
  for (int k0 = 0; k0 < K; k0 += 64) {
    __syncthreads();
#pragma unroll
    for (int j = 0; j < 4; ++j) {
      int idx = (wave * 4 + j) * 64 + lane;   // atom index, LDS-linear
      int r = idx >> 3;
      int c8 = (idx & 7) ^ (r & 7);           // swizzled k8 slot
      load_lds16(A + (size_t)(row0 + r) * K + (k0 + c8 * 8), &Asl[idx * 8]);
      load_lds16(Bm + (size_t)(col0 + r) * K + (k0 + c8 * 8), &Bsl[idx * 8]);
    }
    __syncthreads();
#pragma unroll
    for (int c = 0; c < 2; ++c) {
      bf16x8 af[4], bfr[4];
#pragma unroll
      for (int mt = 0; mt < 4; ++mt) {
        int r = waveM + mt * 16 + l15;
        af[mt] = *(const bf16x8*)&Asl[(r * 8 + ((c * 4 + quad) ^ (r & 7))) * 8];
      }
#pragma unroll
      for (int nt = 0; nt < 4; ++nt) {
        int r = waveN + nt * 16 + l15;
        bfr[nt] = *(const bf16x8*)&Bsl[(r * 8 + ((c * 4 + quad) ^ (r & 7))) * 8];
      }
#pragma unroll
      for (int mt = 0; mt < 4; ++mt)
#pragma unroll
        for (int nt = 0; nt < 4; ++nt) {
          if (SWAP)
            acc[mt][nt] = __builtin_amdgcn_mfma_f32_16x16x32_bf16(
                bfr[nt], af[mt], acc[mt][nt], 0, 0, 0);
          else
            acc[mt][nt] = __builtin_amdgcn_mfma_f32_16x16x32_bf16(
                af[mt], bfr[nt], acc[mt][nt], 0, 0, 0);
        }
    }
  }
}

// ==================== R6: 256x256 8-phase pipelined QKV GEMM ===============
// 8 waves (2M x 4N), per-wave C block 128x64 (8x4 f32x4 acc).
// LDS 128 KiB: A region [2 dbuf][2 half: rows 0-127 / 128-255][128x64 bf16],
//              B region likewise (half = cols 0-127 / 128-255).
// Iteration i computes K-tiles kt=2i (d0, phases P0-P3) and 2i+1 (d1, P4-P7),
// quadrant order per tile: (m0,n0),(m0,n1),(m1,n0),(m1,n1); A frags held
// across 2 phases, B n0/n1 frags held across the 4 phases.
// Stage slots (1 half-tile = 2 global_load_lds/thread per phase):
//   P0: d1.Ah0<-kt2i+1  P1: d1.Ah1<-kt2i+1  P2: d0.Bh0<-kt2i+2
//   P3: d0.Ah0<-kt2i+2  P4: d0.Ah1<-kt2i+2  P5: d0.Bh1<-kt2i+2
//   P6: d1.Bh0<-kt2i+3  P7: d1.Bh1<-kt2i+3
// Every slot writes a region whose previous contents were last ds_read in an
// earlier phase (>=1 barrier separation; a wave only passes a phase's second
// barrier after its explicit lgkmcnt(0)). Counted waits: vmcnt(4) at end of
// P3 (d1 complete for P4) and end of P7 (d0 complete for next P0) -- the 4
// newest loads (2 slots) are exactly the ones not yet needed.

#define BARR asm volatile("s_barrier" ::: "memory")
#define LGKM0 asm volatile("s_waitcnt lgkmcnt(0)" ::: "memory")
#define VMW4 asm volatile("s_waitcnt vmcnt(4)" ::: "memory")
#define VMW0 asm volatile("s_waitcnt vmcnt(0)" ::: "memory")

#define STG(OP, DB, HF, KOFF) do {                                          \
    const u16* gb_ = ((OP) ? Bg : Ag) + (HF) * 262144 + (KOFF);             \
    u16* lb_ = S + ((OP) ? 32768 : 0) + (DB) * 16384 + (HF) * 8192;         \
    load_lds16(gb_ + off0, lb_ + tid * 8);                                  \
    load_lds16(gb_ + off1, lb_ + (tid + 512) * 8);                          \
  } while (0)

#define LDA(DB, MH) do {                                                    \
    const u16* ab_ = S + (DB) * 16384 + wm * 8192;                          \
    _Pragma("unroll") for (int mt_ = 0; mt_ < 4; ++mt_) {                   \
      int rA_ = (MH) * 64 + mt_ * 16 + l15;                                 \
      int sw_ = rA_ & 7;                                                    \
      af[mt_][0] = *(const bf16x8_a*)(ab_ + (rA_ * 8 + (quad ^ sw_)) * 8);  \
      af[mt_][1] = *(const bf16x8_a*)(ab_ + (rA_ * 8 + ((4 + quad) ^ sw_)) * 8); \
    } } while (0)

#define LDB(DB, NH, DST) do {                                               \
    const u16* bb_ = S + 32768 + (DB) * 16384 + (wn >> 1) * 8192;           \
    _Pragma("unroll") for (int nt_ = 0; nt_ < 2; ++nt_) {                   \
      int rB_ = (wn & 1) * 64 + (NH) * 32 + nt_ * 16 + l15;                 \
      int sw_ = rB_ & 7;                                                    \
      DST[nt_][0] = *(const bf16x8_a*)(bb_ + (rB_ * 8 + (quad ^ sw_)) * 8); \
      DST[nt_][1] = *(const bf16x8_a*)(bb_ + (rB_ * 8 + ((4 + quad) ^ sw_)) * 8); \
    } } while (0)

#define MMQ(MH, NH, BFR) do {                                               \
    __builtin_amdgcn_s_setprio(1);                                          \
    _Pragma("unroll") for (int c_ = 0; c_ < 2; ++c_)                        \
      _Pragma("unroll") for (int mt_ = 0; mt_ < 4; ++mt_)                   \
        _Pragma("unroll") for (int nt_ = 0; nt_ < 2; ++nt_) {               \
          if (VM)                                                           \
            acc[(MH) * 4 + mt_][(NH) * 2 + nt_] =                           \
                __builtin_amdgcn_mfma_f32_16x16x32_bf16(                    \
                    BFR[nt_][c_], af[mt_][c_],                              \
                    acc[(MH) * 4 + mt_][(NH) * 2 + nt_], 0, 0, 0);          \
          else                                                              \
            acc[(MH) * 4 + mt_][(NH) * 2 + nt_] =                           \
                __builtin_amdgcn_mfma_f32_16x16x32_bf16(                    \
                    af[mt_][c_], BFR[nt_][c_],                              \
                    acc[(MH) * 4 + mt_][(NH) * 2 + nt_], 0, 0, 0);          \
        }                                                                   \
    __builtin_amdgcn_s_setprio(0);                                          \
  } while (0)

template <bool VM>
__device__ __forceinline__ void qkv_core(const u16* __restrict__ Ag,
                                         const u16* __restrict__ Bg,
                                         u16* __restrict__ S, int tid,
                                         f32x4 acc[8][4]) {
  const int lane = tid & 63;
  const int wave = tid >> 6;
  const int quad = lane >> 4;
  const int l15 = lane & 15;
  const int wm = wave >> 2;
  const int wn = wave & 3;

  // staging geometry: 2 atoms/thread per half-tile; source k8 pre-swizzled,
  // LDS dest linear (both-sides-or-neither rule), read applies same XOR.
  const int r0_ = tid >> 3;
  const u32 off0 = (u32)r0_ * 2048u + (u32)(((tid & 7) ^ (r0_ & 7)) * 8);
  const int i1_ = tid + 512;
  const int r1_ = i1_ >> 3;
  const u32 off1 = (u32)r1_ * 2048u + (u32)(((i1_ & 7) ^ (r1_ & 7)) * 8);

  bf16x8 af[4][2], bn0[2][2], bn1[2][2];

  // prologue: kt0 (d0 all halves) + kt1.B (d1), in steady-state slot order
  STG(1, 0, 0, 0);     // kt0.Bh0
  STG(0, 0, 0, 0);     // kt0.Ah0
  STG(0, 0, 1, 0);     // kt0.Ah1
  STG(1, 0, 1, 0);     // kt0.Bh1
  STG(1, 1, 0, 64);    // kt1.Bh0
  STG(1, 1, 1, 64);    // kt1.Bh1
  VMW4;                // first 8 loads (= kt0 complete) retired
  BARR;

#pragma unroll 1
  for (int kb = 0; kb < 1920; kb += 128) {
    // ---- K-tile 2i from d0 ----
    // P0
    LDA(0, 0); LDB(0, 0, bn0); STG(0, 1, 0, kb + 64);
    BARR; LGKM0; MMQ(0, 0, bn0); BARR;
    // P1
    LDB(0, 1, bn1); STG(0, 1, 1, kb + 64);
    BARR; LGKM0; MMQ(0, 1, bn1); BARR;
    // P2
    LDA(0, 1); STG(1, 0, 0, kb + 128);
    BARR; LGKM0; MMQ(1, 0, bn0); BARR;
    // P3
    STG(0, 0, 0, kb + 128);
    BARR; MMQ(1, 1, bn1); VMW4; BARR;
    // ---- K-tile 2i+1 from d1 ----
    // P4
    LDA(1, 0); LDB(1, 0, bn0); STG(0, 0, 1, kb + 128);
    BARR; LGKM0; MMQ(0, 0, bn0); BARR;
    // P5
    LDB(1, 1, bn1); STG(1, 0, 1, kb + 128);
    BARR; LGKM0; MMQ(0, 1, bn1); BARR;
    // P6
    LDA(1, 1); STG(1, 1, 0, kb + 192);
    BARR; LGKM0; MMQ(1, 0, bn0); BARR;
    // P7
    STG(1, 1, 1, kb + 192);
    BARR; MMQ(1, 1, bn1); VMW4; BARR;
  }

  // tail: kb = 1920, d0 = kt30, d1 = kt31 (A halves staged here at T0/T1)
  LDA(0, 0); LDB(0, 0, bn0); STG(0, 1, 0, 1984);
  BARR; LGKM0; MMQ(0, 0, bn0); BARR;
  LDB(0, 1, bn1); STG(0, 1, 1, 1984);
  BARR; LGKM0; MMQ(0, 1, bn1); BARR;
  LDA(0, 1);
  BARR; LGKM0; MMQ(1, 0, bn0); BARR;
  BARR; MMQ(1, 1, bn1); VMW0; BARR;
  LDA(1, 0); LDB(1, 0, bn0);
  BARR; LGKM0; MMQ(0, 0, bn0); BARR;
  LDB(1, 1, bn1);
  BARR; LGKM0; MMQ(0, 1, bn1); BARR;
  LDA(1, 1);
  BARR; LGKM0; MMQ(1, 0, bn0); BARR;
  BARR; MMQ(1, 1, bn1); BARR;
}

#undef STG
#undef LDA
#undef LDB
#undef MMQ

// grid (24, 16), 512 threads. bx<16: Q/K with fused RoPE; bx>=16: V^T.
__global__ __launch_bounds__(512, 2)
void gemm_qkv(const u16* __restrict__ A, const u16* __restrict__ Bm,
              u16* __restrict__ qkv, u16* __restrict__ vt) {
  __shared__ __align__(16) u16 S[65536];  // 128 KiB

  const int tid = threadIdx.x;
  // XCD-aware bijective swizzle: 384 blocks, 48 contiguous per XCD
  // (2 full row-panels of 24 col-blocks -> A-panel L2 reuse per XCD).
  int orig = blockIdx.y * 24 + blockIdx.x;
  int swz = (orig & 7) * 48 + (orig >> 3);
  const int bx = swz % 24;
  const int by = swz / 24;
  const int row0 = by * 256;
  const int col0 = bx * 256;
  const bool vmode = bx >= 16;

  const u16* Ag = A + (size_t)row0 * 2048;
  const u16* Bg = Bm + (size_t)col0 * 2048;

  f32x4 acc[8][4] = {};
  if (vmode) qkv_core<true>(Ag, Bg, S, tid, acc);
  else       qkv_core<false>(Ag, Bg, S, tid, acc);

  const int lane = tid & 63;
  const int wave = tid >> 6;
  const int quad = lane >> 4;
  const int l15 = lane & 15;
  const int wm = wave >> 2;
  const int wn = wave & 3;

  const int which = col0 >> 11;           // 0=q 1=k 2=v
  const float qs = (which == 0) ? 0.12751744f : 1.0f;  // log2e/sqrt(128)

  // acc -> 256x256 bf16 tile in S, atom-XOR swizzled (32 atoms/row)
#pragma unroll
  for (int mh = 0; mh < 2; ++mh)
#pragma unroll
    for (int nh = 0; nh < 2; ++nh)
#pragma unroll
      for (int mt = 0; mt < 4; ++mt)
#pragma unroll
        for (int nt = 0; nt < 2; ++nt)
#pragma unroll
          for (int r = 0; r < 4; ++r) {
            int el;
            if (vmode) {  // C^T: rows = d (256), cols = s (256)
              int dd = wn * 64 + nh * 32 + nt * 16 + quad * 4 + r;
              int ss = wm * 128 + mh * 64 + mt * 16 + l15;
              el = dd * 256 + (((ss >> 3) ^ (dd & 31)) * 8) + (ss & 7);
            } else {      // rows = s, cols = d (2 heads)
              int ss = wm * 128 + mh * 64 + mt * 16 + quad * 4 + r;
              int dd = wn * 64 + nh * 32 + nt * 16 + l15;
              el = ss * 256 + (((dd >> 3) ^ (ss & 31)) * 8) + (dd & 7);
            }
            S[el] = f2bf(acc[mh * 4 + mt][nh * 2 + nt][r] * qs);
          }
  __syncthreads();

  const int a = lane & 7;     // atom within a 64-elem half
  const int sg = lane >> 3;   // row-in-group
  const int h0 = (col0 >> 7) & 15;
  const int brow = row0 >> 11;
  const int sbase = row0 & 2047;

  if (!vmode) {
    const float c1 = 0.2076205059304601f;   // log2(10000)/64
    const float c2 = 2.6514961294723187f;   // log2(2*pi)
#pragma unroll
    for (int pass = 0; pass < 4; ++pass) {
      int s_l = pass * 64 + wave * 8 + sg;
      int s2048 = sbase + s_l;
      int sw = s_l & 31;
#pragma unroll
      for (int hh = 0; hh < 2; ++hh) {
        bf16x8 x1 = *(const bf16x8_a*)&S[s_l * 256 + (((hh * 16 + a) ^ sw) * 8)];
        bf16x8 x2 = *(const bf16x8_a*)&S[s_l * 256 + (((hh * 16 + a + 8) ^ sw) * 8)];
        u16 o1[8], o2[8];
#pragma unroll
        for (int e = 0; e < 8; ++e) {
          float j = (float)(a * 8 + e);
          float rev = (float)s2048 * __builtin_amdgcn_exp2f(-c1 * j - c2);
          rev = __builtin_amdgcn_fractf(rev);
          float sn = __builtin_amdgcn_sinf(rev);
          float cs = __builtin_amdgcn_cosf(rev);
          float v1 = (float)x1[e], v2 = (float)x2[e];
          o1[e] = f2bf(v1 * cs - v2 * sn);
          o2[e] = f2bf(v2 * cs + v1 * sn);
        }
        size_t base = ((((size_t)which * 2 + brow) * 16 + (h0 + hh)) * SEQ +
                       s2048) * HD + a * 8;
        *(uint4_a*)&qkv[base] = *(uint4*)o1;
        *(uint4_a*)&qkv[base + 64] = *(uint4*)o2;
      }
    }
  } else {  // V: transposed copy-out, vt[b,h,d,s]
#pragma unroll
    for (int pass = 0; pass < 4; ++pass) {
      int d_l = pass * 64 + wave * 8 + sg;      // 0..255 (2 heads)
      int h = h0 + (d_l >> 7);
      int dw = d_l & 31;
      size_t rb = (((size_t)brow * 16 + h) * HD + (d_l & 127)) * SEQ + sbase;
#pragma unroll
      for (int g = 0; g < 4; ++g) {
        int As = g * 8 + a;
        bf16x8 y = *(const bf16x8_a*)&S[d_l * 256 + ((As ^ dw) * 8)];
        *(uint4_a*)&vt[rb + As * 8] = *(uint4_a*)&y;
      }
    }
  }
}

// ---------------- output GEMM: fp32 + bias ----------------
__global__ __launch_bounds__(256, 3)
void gemm_out(const u16* __restrict__ A, const u16* __restrict__ Bm,
              float* __restrict__ C, const float* __restrict__ bias, int N,
              int K) {
  __shared__ __align__(16) u16 Smem[2][128 * 64];
  const int tid = threadIdx.x;
  const int lane = tid & 63;
  const int wave = tid >> 6;
  const int quad = lane >> 4;
  const int l15 = lane & 15;
  const int row0 = blockIdx.y * 128;
  const int col0 = blockIdx.x * 128;
  const int waveM = (wave & 1) * 64;
  const int waveN = (wave >> 1) * 64;

  f32x4 acc[4][4] = {};
  gemm_core<false>(A, Bm, row0, col0, K, Smem[0], Smem[1], wave, lane, quad,
                   l15, waveM, waveN, acc);

#pragma unroll
  for (int nt = 0; nt < 4; ++nt) {
    int d = col0 + waveN + nt * 16 + l15;
    float bv = bias[d];
#pragma unroll
    for (int mt = 0; mt < 4; ++mt) {
#pragma unroll
      for (int r = 0; r < 4; ++r) {
        int row = row0 + waveM + mt * 16 + quad * 4 + r;
        C[(size_t)row * N + d] = acc[mt][nt][r] + bv;
      }
    }
  }
}

// ---------------- Flash attention (R5: no online max) ----------------
__global__ __launch_bounds__(256, 2)
void attn_kernel(const u16* __restrict__ qkv, const u16* __restrict__ vt,
                 u16* __restrict__ attn_out) {
  __shared__ __align__(16) u16 Kl[64 * 128];     // [kv][hd] swizzled atoms
  __shared__ __align__(16) u16 Vl[128 * 64];     // [d][kv] swizzled atoms
  __shared__ __align__(16) u16 Pl[4][32 * 64];   // per-wave [q][kv] swizzled

  const int tid = threadIdx.x;
  const int lane = tid & 63;
  const int wave = tid >> 6;
  const int quad = lane >> 4;
  const int l15 = lane & 15;
  const int q0 = blockIdx.x * 128;
  const int bh = blockIdx.y;
  const size_t SD = (size_t)SEQ * HD;

  const u16* Q = qkv + (size_t)bh * SD;          // which=0 (pre-scaled)
  const u16* Kg = qkv + (size_t)(32 + bh) * SD;  // which=1
  const u16* Vg = vt + (size_t)bh * SD;          // [d][s]

  bf16x8 onesf;
#pragma unroll
  for (int e = 0; e < 8; ++e)
    onesf[e] = (l15 == 0) ? (__bf16)1.0f : (__bf16)0.0f;

  bf16x8 qf[2][4];  // Q[q=mt*16+l15][hd=c*32+quad*8+j]
#pragma unroll
  for (int mt = 0; mt < 2; ++mt) {
    int qrow = q0 + wave * 32 + mt * 16 + l15;
#pragma unroll
    for (int c = 0; c < 4; ++c)
      qf[mt][c] = *(const bf16x8*)(Q + (size_t)qrow * HD + c * 32 + quad * 8);
  }

  f32x4 of[9][2] = {};   // of[0..7]: O^T[d][q]; of[8] row0: l (ones frag)
  u16* pw = &Pl[wave][0];

  for (int kv0 = 0; kv0 < SEQ; kv0 += 64) {
    __syncthreads();
#pragma unroll
    for (int j = 0; j < 4; ++j) {
      int idx = (wave * 4 + j) * 64 + lane;
      {  // K: 64 rows x 16 atoms, swizzle ^(row&15)
        int r = idx >> 4, cs = idx & 15;
        int cc = cs ^ (r & 15);
        load_lds16(Kg + (size_t)(kv0 + r) * HD + cc * 8, &Kl[idx * 8]);
      }
      {  // VT: 128 rows x 8 atoms, swizzle ^(row&7)
        int r = idx >> 3, cs = idx & 7;
        int cc = cs ^ (r & 7);
        load_lds16(Vg + (size_t)r * SEQ + kv0 + cc * 8, &Vl[idx * 8]);
      }
    }
    __syncthreads();

    // S^T tiles: sc[nt][mt], rows kv=nt*16+quad*4+r, cols q=mt*16+l15
    f32x4 sc[4][2] = {};
#pragma unroll
    for (int c = 0; c < 4; ++c) {
      bf16x8 kf[4];
#pragma unroll
      for (int nt = 0; nt < 4; ++nt)
        kf[nt] = *(const bf16x8*)&Kl[((nt * 16 + l15) * 16 +
                                      ((c * 4 + quad) ^ l15)) * 8];
#pragma unroll
      for (int nt = 0; nt < 4; ++nt)
#pragma unroll
        for (int mt = 0; mt < 2; ++mt)
          sc[nt][mt] = __builtin_amdgcn_mfma_f32_16x16x32_bf16(
              kf[nt], qf[mt][c], sc[nt][mt], 0, 0, 0);
    }

    // P = exp2(sc); truncate-pack via v_perm; b64 writes
#pragma unroll
    for (int nt = 0; nt < 4; ++nt) {
#pragma unroll
      for (int mt = 0; mt < 2; ++mt) {
        float p0 = __builtin_amdgcn_exp2f(sc[nt][mt][0]);
        float p1 = __builtin_amdgcn_exp2f(sc[nt][mt][1]);
        float p2 = __builtin_amdgcn_exp2f(sc[nt][mt][2]);
        float p3 = __builtin_amdgcn_exp2f(sc[nt][mt][3]);
        u32 lo = __builtin_amdgcn_perm(__float_as_uint(p1),
                                       __float_as_uint(p0), 0x07060302u);
        u32 hi = __builtin_amdgcn_perm(__float_as_uint(p3),
                                       __float_as_uint(p2), 0x07060302u);
        int row = mt * 16 + l15;
        int a = nt * 2 + (quad >> 1);
        int idx16 = (row * 8 + (a ^ (l15 & 7))) * 8 + (quad & 1) * 4;
        uint2 pk; pk.x = lo; pk.y = hi;
        *(uint2_a*)&pw[idx16] = pk;
      }
    }

    // O^T += V^T.P ; dt=8 uses the register ones-frag -> row sums (l)
#pragma unroll
    for (int c = 0; c < 2; ++c) {
      bf16x8 pf[2];
#pragma unroll
      for (int mt = 0; mt < 2; ++mt)
        pf[mt] = *(const bf16x8_a*)&pw[((mt * 16 + l15) * 8 +
                                        ((c * 4 + quad) ^ (l15 & 7))) * 8];
#pragma unroll
      for (int dt = 0; dt < 9; ++dt) {
        bf16x8 vf = (dt < 8)
                        ? *(const bf16x8*)&Vl[((dt * 16 + l15) * 8 +
                                               ((c * 4 + quad) ^ (l15 & 7))) * 8]
                        : onesf;
#pragma unroll
        for (int mt = 0; mt < 2; ++mt)
          of[dt][mt] = __builtin_amdgcn_mfma_f32_16x16x32_bf16(
              vf, pf[mt], of[dt][mt], 0, 0, 0);
      }
    }
  }

  // l lives at of[8][mt][0] on quad-0 lanes (C row 0); broadcast by shfl.
  const int b = bh >> 4, h = bh & 15;
#pragma unroll
  for (int mt = 0; mt < 2; ++mt) {
    float lsum = __shfl(of[8][mt][0], l15, 64);
    float inv = 1.f / lsum;
    int s = q0 + wave * 32 + mt * 16 + l15;
    size_t rowb = ((size_t)b * SEQ + s) * DMODEL + h * HD;
#pragma unroll
    for (int dt = 0; dt < 8; ++dt) {
      ushort4 ov;
      ov.x = f2bf(of[dt][mt][0] * inv);
      ov.y = f2bf(of[dt][mt][1] * inv);
      ov.z = f2bf(of[dt][mt][2] * inv);
      ov.w = f2bf(of[dt][mt][3] * inv);
      *(ushort4*)&attn_out[rowb + dt * 16 + quad * 4] = ov;
    }
  }
}

extern "C" void kernel_launch(void* const* d_in, const int* in_sizes, int n_in,
                              void* d_out, int out_size, void* d_ws,
                              size_t ws_size, hipStream_t stream) {
  const float* x = (const float*)d_in[0];
  const float* Wq = (const float*)d_in[1];
  const float* Wk = (const float*)d_in[2];
  const float* Wv = (const float*)d_in[3];
  const float* Wo = (const float*)d_in[4];
  const float* bo = (const float*)d_in[5];
  float* out = (float*)d_out;

  char* ws = (char*)d_ws;
  u16* xb = (u16*)(ws);                              // 16 MiB
  u16* wqkv = (u16*)(ws + (size_t)(16 << 20));       // 24 MiB
  u16* wob = (u16*)(ws + (size_t)(40 << 20));        // 8 MiB
  u16* qkv = (u16*)(ws + (size_t)(48 << 20));        // 48 MiB: Q | K | vt
  u16* vt = qkv + (size_t)2 * 8388608;               // vt in the V slot
  u16* attn = xb;                                    // reuse after GEMMs

  // fp32 -> bf16 (one fused launch)
  conv_all<<<24576, 256, 0, stream>>>(x, Wq, Wk, Wv, Wo, xb, wqkv, wob);

  // Q,K (fused RoPE) + V^T in one 256x256-tile 8-phase launch
  gemm_qkv<<<dim3(24, 16), 512, 0, stream>>>(xb, wqkv, qkv, vt);
  // flash attention
  attn_kernel<<<dim3(16, 32), 256, 0, stream>>>(qkv, vt, attn);
  // out = attn @ wob^T + bo
  gemm_out<<<dim3(16, 32), 256, 0, stream>>>(attn, wob, out, bo, 2048, 2048);
}

// Round 2
// 363.031 us; speedup vs baseline: 1.0342x; 1.0283x over previous
//
#include <hip/hip_runtime.h>
#include <stdint.h>

// MultiHeadAttention: B=2, S=2048, D=2048, H=16, Dh=128, fp32 in/out.
// R7: attn_kernel gets T3-depth-2/T4/T5: K/V LDS double-buffer (80 KiB,
//     still 2 blocks/CU), stage(t+2) issued post-barrier with counted
//     s_waitcnt vmcnt(8) (never 0 until the tail) so staging latency hides
//     under one full compute phase; s_setprio(1) around QK^T and PV MFMA
//     clusters. gemm_qkv / gemm_out / conv_all byte-identical to R6 to
//     isolate the attn delta.

#define SEQ 2048
#define HD 128
#define DMODEL 2048

typedef __bf16 bf16x8 __attribute__((ext_vector_type(8)));
typedef float f32x4 __attribute__((ext_vector_type(4)));
typedef unsigned short u16;
typedef unsigned int u32;

typedef bf16x8 __attribute__((may_alias)) bf16x8_a;
typedef uint2 __attribute__((may_alias)) uint2_a;
typedef uint4 __attribute__((may_alias)) uint4_a;

__device__ __forceinline__ u16 f2bf(float f) {
  unsigned int u = __float_as_uint(f);
  u += 0x7fff + ((u >> 16) & 1);   // RNE; inputs are finite normals
  return (u16)(u >> 16);
}

typedef __attribute__((address_space(1))) void* gas_t;
typedef __attribute__((address_space(3))) void* las_t;
// async global->LDS, 16B/lane. LDS dest must be uniform base + lane*16.
__device__ __forceinline__ void load_lds16(const void* g, void* l) {
  __builtin_amdgcn_global_load_lds((gas_t)(uintptr_t)g,
                                   (las_t)(uint32_t)(uintptr_t)l, 16, 0, 0);
}

// ---------------- fp32 -> bf16 convert (all 5 tensors, one launch) ---------
__global__ void conv_all(const float* __restrict__ x,
                         const float* __restrict__ wq,
                         const float* __restrict__ wk,
                         const float* __restrict__ wv,
                         const float* __restrict__ wo,
                         u16* __restrict__ xb, u16* __restrict__ wqkv,
                         u16* __restrict__ wob) {
  int i = blockIdx.x * 256 + threadIdx.x;  // float4 index
  const float* src;
  u16* dst;
  int off;
  if (i < 2097152) { src = x; dst = xb; off = i; }
  else if (i < 3145728) { src = wq; dst = wqkv; off = i - 2097152; }
  else if (i < 4194304) { src = wk; dst = wqkv + 4194304; off = i - 3145728; }
  else if (i < 5242880) { src = wv; dst = wqkv + 8388608; off = i - 4194304; }
  else { src = wo; dst = wob; off = i - 5242880; }
  float4 v = ((const float4*)src)[off];
  ushort4 o;
  o.x = f2bf(v.x); o.y = f2bf(v.y); o.z = f2bf(v.z); o.w = f2bf(v.w);
  ((ushort4*)dst)[off] = o;
}

// ---------------- shared 128x128 GEMM core (kept for gemm_out) -------------
template <bool SWAP>
__device__ __forceinline__ void gemm_core(
    const u16* __restrict__ A, const u16* __restrict__ Bm, int row0, int col0,
    int K, u16* Asl, u16* Bsl, int wave, int lane, int quad, int l15,
    int waveM, int waveN, f32x4 acc[4][4]) {
  for (int k0 = 0; k0 < K; k0 += 64) {
    __syncthreads();
#pragma unroll
    for (int j = 0; j < 4; ++j) {
      int idx = (wave * 4 + j) * 64 + lane;   // atom index, LDS-linear
      int r = idx >> 3;
      int c8 = (idx & 7) ^ (r & 7);           // swizzled k8 slot
      load_lds16(A + (size_t)(row0 + r) * K + (k0 + c8 * 8), &Asl[idx * 8]);
      load_lds16(Bm + (size_t)(col0 + r) * K + (k0 + c8 * 8), &Bsl[idx * 8]);
    }
    __syncthreads();
#pragma unroll
    for (int c = 0; c < 2; ++c) {
      bf16x8 af[4], bfr[4];
#pragma unroll
      for (int mt = 0; mt < 4; ++mt) {
        int r = waveM + mt * 16 + l15;
        af[mt] = *(const bf16x8*)&Asl[(r * 8 + ((c * 4 + quad) ^ (r & 7))) * 8];
      }
#pragma unroll
      for (int nt = 0; nt < 4; ++nt) {
        int r = waveN + nt * 16 + l15;
        bfr[nt] = *(const bf16x8*)&Bsl[(r * 8 + ((c * 4 + quad) ^ (r & 7))) * 8];
      }
#pragma unroll
      for (int mt = 0; mt < 4; ++mt)
#pragma unroll
        for (int nt = 0; nt < 4; ++nt) {
          if (SWAP)
            acc[mt][nt] = __builtin_amdgcn_mfma_f32_16x16x32_bf16(
                bfr[nt], af[mt], acc[mt][nt], 0, 0, 0);
          else
            acc[mt][nt] = __builtin_amdgcn_mfma_f32_16x16x32_bf16(
                af[mt], bfr[nt], acc[mt][nt], 0, 0, 0);
        }
    }
  }
}

// ==================== 256x256 8-phase pipelined QKV GEMM (R6) ==============
#define BARR asm volatile("s_barrier" ::: "memory")
#define LGKM0 asm volatile("s_waitcnt lgkmcnt(0)" ::: "memory")
#define VMW4 asm volatile("s_waitcnt vmcnt(4)" ::: "memory")
#define VMW8 asm volatile("s_waitcnt vmcnt(8)" ::: "memory")
#define VMW0 asm volatile("s_waitcnt vmcnt(0)" ::: "memory")

#define STG(OP, DB, HF, KOFF) do {                                          \
    const u16* gb_ = ((OP) ? Bg : Ag) + (HF) * 262144 + (KOFF);             \
    u16* lb_ = S + ((OP) ? 32768 : 0) + (DB) * 16384 + (HF) * 8192;         \
    load_lds16(gb_ + off0, lb_ + tid * 8);                                  \
    load_lds16(gb_ + off1, lb_ + (tid + 512) * 8);                          \
  } while (0)

#define LDA(DB, MH) do {                                                    \
    const u16* ab_ = S + (DB) * 16384 + wm * 8192;                          \
    _Pragma("unroll") for (int mt_ = 0; mt_ < 4; ++mt_) {                   \
      int rA_ = (MH) * 64 + mt_ * 16 + l15;                                 \
      int sw_ = rA_ & 7;                                                    \
      af[mt_][0] = *(const bf16x8_a*)(ab_ + (rA_ * 8 + (quad ^ sw_)) * 8);  \
      af[mt_][1] = *(const bf16x8_a*)(ab_ + (rA_ * 8 + ((4 + quad) ^ sw_)) * 8); \
    } } while (0)

#define LDB(DB, NH, DST) do {                                               \
    const u16* bb_ = S + 32768 + (DB) * 16384 + (wn >> 1) * 8192;           \
    _Pragma("unroll") for (int nt_ = 0; nt_ < 2; ++nt_) {                   \
      int rB_ = (wn & 1) * 64 + (NH) * 32 + nt_ * 16 + l15;                 \
      int sw_ = rB_ & 7;                                                    \
      DST[nt_][0] = *(const bf16x8_a*)(bb_ + (rB_ * 8 + (quad ^ sw_)) * 8); \
      DST[nt_][1] = *(const bf16x8_a*)(bb_ + (rB_ * 8 + ((4 + quad) ^ sw_)) * 8); \
    } } while (0)

#define MMQ(MH, NH, BFR) do {                                               \
    __builtin_amdgcn_s_setprio(1);                                          \
    _Pragma("unroll") for (int c_ = 0; c_ < 2; ++c_)                        \
      _Pragma("unroll") for (int mt_ = 0; mt_ < 4; ++mt_)                   \
        _Pragma("unroll") for (int nt_ = 0; nt_ < 2; ++nt_) {               \
          if (VM)                                                           \
            acc[(MH) * 4 + mt_][(NH) * 2 + nt_] =                           \
                __builtin_amdgcn_mfma_f32_16x16x32_bf16(                    \
                    BFR[nt_][c_], af[mt_][c_],                              \
                    acc[(MH) * 4 + mt_][(NH) * 2 + nt_], 0, 0, 0);          \
          else                                                              \
            acc[(MH) * 4 + mt_][(NH) * 2 + nt_] =                           \
                __builtin_amdgcn_mfma_f32_16x16x32_bf16(                    \
                    af[mt_][c_], BFR[nt_][c_],                              \
                    acc[(MH) * 4 + mt_][(NH) * 2 + nt_], 0, 0, 0);          \
        }                                                                   \
    __builtin_amdgcn_s_setprio(0);                                          \
  } while (0)

template <bool VM>
__device__ __forceinline__ void qkv_core(const u16* __restrict__ Ag,
                                         const u16* __restrict__ Bg,
                                         u16* __restrict__ S, int tid,
                                         f32x4 acc[8][4]) {
  const int lane = tid & 63;
  const int wave = tid >> 6;
  const int quad = lane >> 4;
  const int l15 = lane & 15;
  const int wm = wave >> 2;
  const int wn = wave & 3;

  const int r0_ = tid >> 3;
  const u32 off0 = (u32)r0_ * 2048u + (u32)(((tid & 7) ^ (r0_ & 7)) * 8);
  const int i1_ = tid + 512;
  const int r1_ = i1_ >> 3;
  const u32 off1 = (u32)r1_ * 2048u + (u32)(((i1_ & 7) ^ (r1_ & 7)) * 8);

  bf16x8 af[4][2], bn0[2][2], bn1[2][2];

  // prologue: kt0 (d0 all halves) + kt1.B (d1), in steady-state slot order
  STG(1, 0, 0, 0);     // kt0.Bh0
  STG(0, 0, 0, 0);     // kt0.Ah0
  STG(0, 0, 1, 0);     // kt0.Ah1
  STG(1, 0, 1, 0);     // kt0.Bh1
  STG(1, 1, 0, 64);    // kt1.Bh0
  STG(1, 1, 1, 64);    // kt1.Bh1
  VMW4;                // first 8 loads (= kt0 complete) retired
  BARR;

#pragma unroll 1
  for (int kb = 0; kb < 1920; kb += 128) {
    // ---- K-tile 2i from d0 ----
    // P0
    LDA(0, 0); LDB(0, 0, bn0); STG(0, 1, 0, kb + 64);
    BARR; LGKM0; MMQ(0, 0, bn0); BARR;
    // P1
    LDB(0, 1, bn1); STG(0, 1, 1, kb + 64);
    BARR; LGKM0; MMQ(0, 1, bn1); BARR;
    // P2
    LDA(0, 1); STG(1, 0, 0, kb + 128);
    BARR; LGKM0; MMQ(1, 0, bn0); BARR;
    // P3
    STG(0, 0, 0, kb + 128);
    BARR; MMQ(1, 1, bn1); VMW4; BARR;
    // ---- K-tile 2i+1 from d1 ----
    // P4
    LDA(1, 0); LDB(1, 0, bn0); STG(0, 0, 1, kb + 128);
    BARR; LGKM0; MMQ(0, 0, bn0); BARR;
    // P5
    LDB(1, 1, bn1); STG(1, 0, 1, kb + 128);
    BARR; LGKM0; MMQ(0, 1, bn1); BARR;
    // P6
    LDA(1, 1); STG(1, 1, 0, kb + 192);
    BARR; LGKM0; MMQ(1, 0, bn0); BARR;
    // P7
    STG(1, 1, 1, kb + 192);
    BARR; MMQ(1, 1, bn1); VMW4; BARR;
  }

  // tail: kb = 1920, d0 = kt30, d1 = kt31 (A halves staged here at T0/T1)
  LDA(0, 0); LDB(0, 0, bn0); STG(0, 1, 0, 1984);
  BARR; LGKM0; MMQ(0, 0, bn0); BARR;
  LDB(0, 1, bn1); STG(0, 1, 1, 1984);
  BARR; LGKM0; MMQ(0, 1, bn1); BARR;
  LDA(0, 1);
  BARR; LGKM0; MMQ(1, 0, bn0); BARR;
  BARR; MMQ(1, 1, bn1); VMW0; BARR;
  LDA(1, 0); LDB(1, 0, bn0);
  BARR; LGKM0; MMQ(0, 0, bn0); BARR;
  LDB(1, 1, bn1);
  BARR; LGKM0; MMQ(0, 1, bn1); BARR;
  LDA(1, 1);
  BARR; LGKM0; MMQ(1, 0, bn0); BARR;
  BARR; MMQ(1, 1, bn1); BARR;
}

#undef STG
#undef LDA
#undef LDB
#undef MMQ

// grid (24, 16), 512 threads. bx<16: Q/K with fused RoPE; bx>=16: V^T.
__global__ __launch_bounds__(512, 2)
void gemm_qkv(const u16* __restrict__ A, const u16* __restrict__ Bm,
              u16* __restrict__ qkv, u16* __restrict__ vt) {
  __shared__ __align__(16) u16 S[65536];  // 128 KiB

  const int tid = threadIdx.x;
  // XCD-aware bijective swizzle: 384 blocks, 48 contiguous per XCD
  int orig = blockIdx.y * 24 + blockIdx.x;
  int swz = (orig & 7) * 48 + (orig >> 3);
  const int bx = swz % 24;
  const int by = swz / 24;
  const int row0 = by * 256;
  const int col0 = bx * 256;
  const bool vmode = bx >= 16;

  const u16* Ag = A + (size_t)row0 * 2048;
  const u16* Bg = Bm + (size_t)col0 * 2048;

  f32x4 acc[8][4] = {};
  if (vmode) qkv_core<true>(Ag, Bg, S, tid, acc);
  else       qkv_core<false>(Ag, Bg, S, tid, acc);

  const int lane = tid & 63;
  const int wave = tid >> 6;
  const int quad = lane >> 4;
  const int l15 = lane & 15;
  const int wm = wave >> 2;
  const int wn = wave & 3;

  const int which = col0 >> 11;           // 0=q 1=k 2=v
  const float qs = (which == 0) ? 0.12751744f : 1.0f;  // log2e/sqrt(128)

  // acc -> 256x256 bf16 tile in S, atom-XOR swizzled (32 atoms/row)
#pragma unroll
  for (int mh = 0; mh < 2; ++mh)
#pragma unroll
    for (int nh = 0; nh < 2; ++nh)
#pragma unroll
      for (int mt = 0; mt < 4; ++mt)
#pragma unroll
        for (int nt = 0; nt < 2; ++nt)
#pragma unroll
          for (int r = 0; r < 4; ++r) {
            int el;
            if (vmode) {  // C^T: rows = d (256), cols = s (256)
              int dd = wn * 64 + nh * 32 + nt * 16 + quad * 4 + r;
              int ss = wm * 128 + mh * 64 + mt * 16 + l15;
              el = dd * 256 + (((ss >> 3) ^ (dd & 31)) * 8) + (ss & 7);
            } else {      // rows = s, cols = d (2 heads)
              int ss = wm * 128 + mh * 64 + mt * 16 + quad * 4 + r;
              int dd = wn * 64 + nh * 32 + nt * 16 + l15;
              el = ss * 256 + (((dd >> 3) ^ (ss & 31)) * 8) + (dd & 7);
            }
            S[el] = f2bf(acc[mh * 4 + mt][nh * 2 + nt][r] * qs);
          }
  __syncthreads();

  const int a = lane & 7;     // atom within a 64-elem half
  const int sg = lane >> 3;   // row-in-group
  const int h0 = (col0 >> 7) & 15;
  const int brow = row0 >> 11;
  const int sbase = row0 & 2047;

  if (!vmode) {
    const float c1 = 0.2076205059304601f;   // log2(10000)/64
    const float c2 = 2.6514961294723187f;   // log2(2*pi)
#pragma unroll
    for (int pass = 0; pass < 4; ++pass) {
      int s_l = pass * 64 + wave * 8 + sg;
      int s2048 = sbase + s_l;
      int sw = s_l & 31;
#pragma unroll
      for (int hh = 0; hh < 2; ++hh) {
        bf16x8 x1 = *(const bf16x8_a*)&S[s_l * 256 + (((hh * 16 + a) ^ sw) * 8)];
        bf16x8 x2 = *(const bf16x8_a*)&S[s_l * 256 + (((hh * 16 + a + 8) ^ sw) * 8)];
        u16 o1[8], o2[8];
#pragma unroll
        for (int e = 0; e < 8; ++e) {
          float j = (float)(a * 8 + e);
          float rev = (float)s2048 * __builtin_amdgcn_exp2f(-c1 * j - c2);
          rev = __builtin_amdgcn_fractf(rev);
          float sn = __builtin_amdgcn_sinf(rev);
          float cs = __builtin_amdgcn_cosf(rev);
          float v1 = (float)x1[e], v2 = (float)x2[e];
          o1[e] = f2bf(v1 * cs - v2 * sn);
          o2[e] = f2bf(v2 * cs + v1 * sn);
        }
        size_t base = ((((size_t)which * 2 + brow) * 16 + (h0 + hh)) * SEQ +
                       s2048) * HD + a * 8;
        *(uint4_a*)&qkv[base] = *(uint4*)o1;
        *(uint4_a*)&qkv[base + 64] = *(uint4*)o2;
      }
    }
  } else {  // V: transposed copy-out, vt[b,h,d,s]
#pragma unroll
    for (int pass = 0; pass < 4; ++pass) {
      int d_l = pass * 64 + wave * 8 + sg;      // 0..255 (2 heads)
      int h = h0 + (d_l >> 7);
      int dw = d_l & 31;
      size_t rb = (((size_t)brow * 16 + h) * HD + (d_l & 127)) * SEQ + sbase;
#pragma unroll
      for (int g = 0; g < 4; ++g) {
        int As = g * 8 + a;
        bf16x8 y = *(const bf16x8_a*)&S[d_l * 256 + ((As ^ dw) * 8)];
        *(uint4_a*)&vt[rb + As * 8] = *(uint4_a*)&y;
      }
    }
  }
}

// ---------------- output GEMM: fp32 + bias ----------------
__global__ __launch_bounds__(256, 3)
void gemm_out(const u16* __restrict__ A, const u16* __restrict__ Bm,
              float* __restrict__ C, const float* __restrict__ bias, int N,
              int K) {
  __shared__ __align__(16) u16 Smem[2][128 * 64];
  const int tid = threadIdx.x;
  const int lane = tid & 63;
  const int wave = tid >> 6;
  const int quad = lane >> 4;
  const int l15 = lane & 15;
  const int row0 = blockIdx.y * 128;
  const int col0 = blockIdx.x * 128;
  const int waveM = (wave & 1) * 64;
  const int waveN = (wave >> 1) * 64;

  f32x4 acc[4][4] = {};
  gemm_core<false>(A, Bm, row0, col0, K, Smem[0], Smem[1], wave, lane, quad,
                   l15, waveM, waveN, acc);

#pragma unroll
  for (int nt = 0; nt < 4; ++nt) {
    int d = col0 + waveN + nt * 16 + l15;
    float bv = bias[d];
#pragma unroll
    for (int mt = 0; mt < 4; ++mt) {
#pragma unroll
      for (int r = 0; r < 4; ++r) {
        int row = row0 + waveM + mt * 16 + quad * 4 + r;
        C[(size_t)row * N + d] = acc[mt][nt][r] + bv;
      }
    }
  }
}

// ---------------- Flash attention (R7: KV dbuf + counted vmcnt) ------------
// grid (S/128, B*H), 4 waves; wave owns 32 Q rows (2 m-tiles).
// Per tile t: compute on buf[t&1]; BARR; stage(t+2)->buf[t&1]; vmcnt(8)
// (stage(t+1) retired, stage(t+2) in flight); BARR. Staging latency hides
// under one full compute phase. setprio(1) around both MFMA clusters.
__global__ __launch_bounds__(256, 2)
void attn_kernel(const u16* __restrict__ qkv, const u16* __restrict__ vt,
                 u16* __restrict__ attn_out) {
  __shared__ __align__(16) u16 Kl[2][64 * 128];   // [kv][hd] swizzled atoms
  __shared__ __align__(16) u16 Vl[2][128 * 64];   // [d][kv] swizzled atoms
  __shared__ __align__(16) u16 Pl[4][32 * 64];    // per-wave [q][kv] swizzled

  const int tid = threadIdx.x;
  const int lane = tid & 63;
  const int wave = tid >> 6;
  const int quad = lane >> 4;
  const int l15 = lane & 15;
  const int q0 = blockIdx.x * 128;
  const int bh = blockIdx.y;
  const size_t SD = (size_t)SEQ * HD;

  const u16* Q = qkv + (size_t)bh * SD;          // which=0 (pre-scaled)
  const u16* Kg = qkv + (size_t)(32 + bh) * SD;  // which=1
  const u16* Vg = vt + (size_t)bh * SD;          // [d][s]

  // ones A-fragment in registers: row m=0 (lanes l15==0) = 1.0, else 0.
  bf16x8 onesf;
#pragma unroll
  for (int e = 0; e < 8; ++e)
    onesf[e] = (l15 == 0) ? (__bf16)1.0f : (__bf16)0.0f;

  // Q fragments first: oldest in the vmcnt FIFO, retired before first use.
  bf16x8 qf[2][4];  // Q[q=mt*16+l15][hd=c*32+quad*8+j]
#pragma unroll
  for (int mt = 0; mt < 2; ++mt) {
    int qrow = q0 + wave * 32 + mt * 16 + l15;
#pragma unroll
    for (int c = 0; c < 4; ++c)
      qf[mt][c] = *(const bf16x8*)(Q + (size_t)qrow * HD + c * 32 + quad * 8);
  }

  f32x4 of[9][2] = {};   // of[0..7]: O^T[d][q]; of[8] row0: l (ones frag)
  u16* pw = &Pl[wave][0];

  // stage one 64-wide KV tile into buffer `buf` (8 loads/thread)
  auto stage = [&](int tile, int buf) {
    int kv0 = tile * 64;
#pragma unroll
    for (int j = 0; j < 4; ++j) {
      int idx = (wave * 4 + j) * 64 + lane;
      {  // K: 64 rows x 16 atoms, swizzle ^(row&15)
        int r = idx >> 4, cs = idx & 15;
        int cc = cs ^ (r & 15);
        load_lds16(Kg + (size_t)(kv0 + r) * HD + cc * 8, &Kl[buf][idx * 8]);
      }
      {  // VT: 128 rows x 8 atoms, swizzle ^(row&7)
        int r = idx >> 3, cs = idx & 7;
        int cc = cs ^ (r & 7);
        load_lds16(Vg + (size_t)r * SEQ + kv0 + cc * 8, &Vl[buf][idx * 8]);
      }
    }
  };

  // prologue: tiles 0 and 1; vmcnt(8) = stage(0) retired (stage(1) in flight)
  stage(0, 0);
  stage(1, 1);
  VMW8;
  BARR;

#pragma unroll 2
  for (int t = 0; t < 32; ++t) {
    const u16* Kb = Kl[t & 1];
    const u16* Vb = Vl[t & 1];

    // S^T tiles: sc[nt][mt], rows kv=nt*16+quad*4+r, cols q=mt*16+l15
    f32x4 sc[4][2] = {};
    __builtin_amdgcn_s_setprio(1);
#pragma unroll
    for (int c = 0; c < 4; ++c) {
      bf16x8 kf[4];
#pragma unroll
      for (int nt = 0; nt < 4; ++nt)
        kf[nt] = *(const bf16x8*)&Kb[((nt * 16 + l15) * 16 +
                                      ((c * 4 + quad) ^ l15)) * 8];
#pragma unroll
      for (int nt = 0; nt < 4; ++nt)
#pragma unroll
        for (int mt = 0; mt < 2; ++mt)
          sc[nt][mt] = __builtin_amdgcn_mfma_f32_16x16x32_bf16(
              kf[nt], qf[mt][c], sc[nt][mt], 0, 0, 0);
    }
    __builtin_amdgcn_s_setprio(0);

    // P = exp2(sc); truncate-pack via v_perm; b64 writes (wave-private Pl)
#pragma unroll
    for (int nt = 0; nt < 4; ++nt) {
#pragma unroll
      for (int mt = 0; mt < 2; ++mt) {
        float p0 = __builtin_amdgcn_exp2f(sc[nt][mt][0]);
        float p1 = __builtin_amdgcn_exp2f(sc[nt][mt][1]);
        float p2 = __builtin_amdgcn_exp2f(sc[nt][mt][2]);
        float p3 = __builtin_amdgcn_exp2f(sc[nt][mt][3]);
        u32 lo = __builtin_amdgcn_perm(__float_as_uint(p1),
                                       __float_as_uint(p0), 0x07060302u);
        u32 hi = __builtin_amdgcn_perm(__float_as_uint(p3),
                                       __float_as_uint(p2), 0x07060302u);
        int row = mt * 16 + l15;
        int a = nt * 2 + (quad >> 1);
        int idx16 = (row * 8 + (a ^ (l15 & 7))) * 8 + (quad & 1) * 4;
        uint2 pk; pk.x = lo; pk.y = hi;
        *(uint2_a*)&pw[idx16] = pk;
      }
    }

    // O^T += V^T.P ; dt=8 uses the register ones-frag -> row sums (l)
    __builtin_amdgcn_s_setprio(1);
#pragma unroll
    for (int c = 0; c < 2; ++c) {
      bf16x8 pf[2];
#pragma unroll
      for (int mt = 0; mt < 2; ++mt)
        pf[mt] = *(const bf16x8_a*)&pw[((mt * 16 + l15) * 8 +
                                        ((c * 4 + quad) ^ (l15 & 7))) * 8];
#pragma unroll
      for (int dt = 0; dt < 9; ++dt) {
        bf16x8 vf = (dt < 8)
                        ? *(const bf16x8*)&Vb[((dt * 16 + l15) * 8 +
                                               ((c * 4 + quad) ^ (l15 & 7))) * 8]
                        : onesf;
#pragma unroll
        for (int mt = 0; mt < 2; ++mt)
          of[dt][mt] = __builtin_amdgcn_mfma_f32_16x16x32_bf16(
              vf, pf[mt], of[dt][mt], 0, 0, 0);
      }
    }
    __builtin_amdgcn_s_setprio(0);

    // all waves done reading buf[t&1]; restage it for tile t+2
    BARR;
    if (t < 30) {
      stage(t + 2, t & 1);
      VMW8;              // stage(t+1) retired; stage(t+2) stays in flight
    } else {
      VMW0;              // tail: drain (covers stage(31) at t=30)
    }
    BARR;
  }

  // l lives at of[8][mt][0] on quad-0 lanes (C row 0); broadcast by shfl.
  const int b = bh >> 4, h = bh & 15;
#pragma unroll
  for (int mt = 0; mt < 2; ++mt) {
    float lsum = __shfl(of[8][mt][0], l15, 64);
    float inv = 1.f / lsum;
    int s = q0 + wave * 32 + mt * 16 + l15;
    size_t rowb = ((size_t)b * SEQ + s) * DMODEL + h * HD;
#pragma unroll
    for (int dt = 0; dt < 8; ++dt) {
      ushort4 ov;
      ov.x = f2bf(of[dt][mt][0] * inv);
      ov.y = f2bf(of[dt][mt][1] * inv);
      ov.z = f2bf(of[dt][mt][2] * inv);
      ov.w = f2bf(of[dt][mt][3] * inv);
      *(ushort4*)&attn_out[rowb + dt * 16 + quad * 4] = ov;
    }
  }
}

extern "C" void kernel_launch(void* const* d_in, const int* in_sizes, int n_in,
                              void* d_out, int out_size, void* d_ws,
                              size_t ws_size, hipStream_t stream) {
  const float* x = (const float*)d_in[0];
  const float* Wq = (const float*)d_in[1];
  const float* Wk = (const float*)d_in[2];
  const float* Wv = (const float*)d_in[3];
  const float* Wo = (const float*)d_in[4];
  const float* bo = (const float*)d_in[5];
  float* out = (float*)d_out;

  char* ws = (char*)d_ws;
  u16* xb = (u16*)(ws);                              // 16 MiB
  u16* wqkv = (u16*)(ws + (size_t)(16 << 20));       // 24 MiB
  u16* wob = (u16*)(ws + (size_t)(40 << 20));        // 8 MiB
  u16* qkv = (u16*)(ws + (size_t)(48 << 20));        // 48 MiB: Q | K | vt
  u16* vt = qkv + (size_t)2 * 8388608;               // vt in the V slot
  u16* attn = xb;                                    // reuse after GEMMs

  // fp32 -> bf16 (one fused launch)
  conv_all<<<24576, 256, 0, stream>>>(x, Wq, Wk, Wv, Wo, xb, wqkv, wob);

  // Q,K (fused RoPE) + V^T in one 256x256-tile 8-phase launch
  gemm_qkv<<<dim3(24, 16), 512, 0, stream>>>(xb, wqkv, qkv, vt);
  // flash attention
  attn_kernel<<<dim3(16, 32), 256, 0, stream>>>(qkv, vt, attn);
  // out = attn @ wob^T + bo
  gemm_out<<<dim3(16, 32), 256, 0, stream>>>(attn, wob, out, bo, 2048, 2048);
}

// Round 3
// 358.936 us; speedup vs baseline: 1.0460x; 1.0114x over previous
//
#include <hip/hip_runtime.h>
#include <stdint.h>

// MultiHeadAttention: B=2, S=2048, D=2048, H=16, Dh=128, fp32 in/out.
// R8: new 256x128-tile / 8-wave / 2-phase-per-K-tile pipelined GEMM core
//     (counted vmcnt, dead-region restaging, setprio) shared by gemm_qkv
//     (grid 768 = exactly 3 CU-rounds, zero tail; was 384 = 1.5 rounds)
//     and gemm_out (grid 256 = exactly 1 round). LDS 96 KiB. Epilogues
//     re-derived for 1-head-per-tile. attn_kernel/conv_all unchanged (R7).

#define SEQ 2048
#define HD 128
#define DMODEL 2048

typedef __bf16 bf16x8 __attribute__((ext_vector_type(8)));
typedef float f32x4 __attribute__((ext_vector_type(4)));
typedef unsigned short u16;
typedef unsigned int u32;

typedef bf16x8 __attribute__((may_alias)) bf16x8_a;
typedef uint2 __attribute__((may_alias)) uint2_a;
typedef uint4 __attribute__((may_alias)) uint4_a;

__device__ __forceinline__ u16 f2bf(float f) {
  unsigned int u = __float_as_uint(f);
  u += 0x7fff + ((u >> 16) & 1);   // RNE; inputs are finite normals
  return (u16)(u >> 16);
}

typedef __attribute__((address_space(1))) void* gas_t;
typedef __attribute__((address_space(3))) void* las_t;
// async global->LDS, 16B/lane. LDS dest must be uniform base + lane*16.
__device__ __forceinline__ void load_lds16(const void* g, void* l) {
  __builtin_amdgcn_global_load_lds((gas_t)(uintptr_t)g,
                                   (las_t)(uint32_t)(uintptr_t)l, 16, 0, 0);
}

// ---------------- fp32 -> bf16 convert (all 5 tensors, one launch) ---------
__global__ void conv_all(const float* __restrict__ x,
                         const float* __restrict__ wq,
                         const float* __restrict__ wk,
                         const float* __restrict__ wv,
                         const float* __restrict__ wo,
                         u16* __restrict__ xb, u16* __restrict__ wqkv,
                         u16* __restrict__ wob) {
  int i = blockIdx.x * 256 + threadIdx.x;  // float4 index
  const float* src;
  u16* dst;
  int off;
  if (i < 2097152) { src = x; dst = xb; off = i; }
  else if (i < 3145728) { src = wq; dst = wqkv; off = i - 2097152; }
  else if (i < 4194304) { src = wk; dst = wqkv + 4194304; off = i - 3145728; }
  else if (i < 5242880) { src = wv; dst = wqkv + 8388608; off = i - 4194304; }
  else { src = wo; dst = wob; off = i - 5242880; }
  float4 v = ((const float4*)src)[off];
  ushort4 o;
  o.x = f2bf(v.x); o.y = f2bf(v.y); o.z = f2bf(v.z); o.w = f2bf(v.w);
  ((ushort4*)dst)[off] = o;
}

// ==================== 256x128-tile 2-phase pipelined GEMM core =============
// 8 waves 4M x 2N (wave tile 64x64, acc[4][4]); BK=64, K=2048 (32 K-tiles).
// LDS 96 KiB: A[2 dbuf][256x64] (64 KB) + B[2 dbuf][128x64] (32 KB).
// Per K-tile t (d = t&1), two phases:
//  P0: ds_read A(mt01) + B(all, held in regs); issue stage(t+1).A -> buf[1-d]
//      (dead: last read P1(t-1)); BARR; lgkmcnt(0); 16 MFMA; BARR.
//  P1: ds_read A(mt23); issue stage(t+2).B -> buf[d] (dead: last read P0(t));
//      BARR; lgkmcnt(0); 16 MFMA; vmcnt(2) (st(t+1) retired, st(t+2).B in
//      flight); BARR.
// Prologue issues st0.A, st0.B, st1.B; vmcnt(2). Tail: t=30 drains vmcnt(0).

#define BARR asm volatile("s_barrier" ::: "memory")
#define LGKM0 asm volatile("s_waitcnt lgkmcnt(0)" ::: "memory")
#define VMW2 asm volatile("s_waitcnt vmcnt(2)" ::: "memory")
#define VMW8 asm volatile("s_waitcnt vmcnt(8)" ::: "memory")
#define VMW0 asm volatile("s_waitcnt vmcnt(0)" ::: "memory")

#define STGA(D, KOFF) do {                                                  \
    const u16* ga_ = Ag + (KOFF);                                           \
    u16* la_ = S + (D) * 16384;                                             \
    load_lds16(ga_ + off[0], la_ + tid * 8);                                \
    load_lds16(ga_ + off[1], la_ + (tid + 512) * 8);                        \
    load_lds16(ga_ + off[2], la_ + (tid + 1024) * 8);                       \
    load_lds16(ga_ + off[3], la_ + (tid + 1536) * 8);                       \
  } while (0)

#define STGB(D, KOFF) do {                                                  \
    const u16* gb_ = Bg + (KOFF);                                           \
    u16* lb_ = S + 32768 + (D) * 8192;                                      \
    load_lds16(gb_ + off[0], lb_ + tid * 8);                                \
    load_lds16(gb_ + off[1], lb_ + (tid + 512) * 8);                        \
  } while (0)

#define LDA2(D, MH) do {                                                    \
    const u16* ab_ = S + (D) * 16384;                                       \
    _Pragma("unroll") for (int mt_ = 0; mt_ < 2; ++mt_) {                   \
      int rA_ = wm * 64 + ((MH) * 2 + mt_) * 16 + l15;                      \
      int sw_ = rA_ & 7;                                                    \
      af[mt_][0] = *(const bf16x8_a*)(ab_ + (rA_ * 8 + (quad ^ sw_)) * 8);  \
      af[mt_][1] = *(const bf16x8_a*)(ab_ + (rA_ * 8 + ((4 + quad) ^ sw_)) * 8); \
    } } while (0)

#define LDB2(D) do {                                                        \
    const u16* bb_ = S + 32768 + (D) * 8192;                                \
    _Pragma("unroll") for (int nt_ = 0; nt_ < 4; ++nt_) {                   \
      int rB_ = wn * 64 + nt_ * 16 + l15;                                   \
      int sw_ = rB_ & 7;                                                    \
      bfr[nt_][0] = *(const bf16x8_a*)(bb_ + (rB_ * 8 + (quad ^ sw_)) * 8); \
      bfr[nt_][1] = *(const bf16x8_a*)(bb_ + (rB_ * 8 + ((4 + quad) ^ sw_)) * 8); \
    } } while (0)

#define MM2(MH) do {                                                        \
    __builtin_amdgcn_s_setprio(1);                                          \
    _Pragma("unroll") for (int c_ = 0; c_ < 2; ++c_)                        \
      _Pragma("unroll") for (int mt_ = 0; mt_ < 2; ++mt_)                   \
        _Pragma("unroll") for (int nt_ = 0; nt_ < 4; ++nt_) {               \
          if (VM)                                                           \
            acc[(MH) * 2 + mt_][nt_] =                                      \
                __builtin_amdgcn_mfma_f32_16x16x32_bf16(                    \
                    bfr[nt_][c_], af[mt_][c_],                              \
                    acc[(MH) * 2 + mt_][nt_], 0, 0, 0);                     \
          else                                                              \
            acc[(MH) * 2 + mt_][nt_] =                                      \
                __builtin_amdgcn_mfma_f32_16x16x32_bf16(                    \
                    af[mt_][c_], bfr[nt_][c_],                              \
                    acc[(MH) * 2 + mt_][nt_], 0, 0, 0);                     \
        }                                                                   \
    __builtin_amdgcn_s_setprio(0);                                          \
  } while (0)

template <bool VM>
__device__ __forceinline__ void mm_core(const u16* __restrict__ Ag,
                                        const u16* __restrict__ Bg,
                                        u16* __restrict__ S, int tid,
                                        f32x4 acc[4][4]) {
  const int lane = tid & 63;
  const int wave = tid >> 6;
  const int quad = lane >> 4;
  const int l15 = lane & 15;
  const int wm = wave >> 1;
  const int wn = wave & 1;

  // staging offsets: atom idx = tid + j*512; row = idx>>3 (stride K=2048);
  // source k8 pre-swizzled by ^(row&7); LDS dest linear (both-sides rule).
  u32 off[4];
#pragma unroll
  for (int j = 0; j < 4; ++j) {
    int idx = tid + j * 512;
    int r = idx >> 3;
    off[j] = (u32)r * 2048u + (u32)(((idx & 7) ^ (r & 7)) * 8);
  }

  bf16x8 af[2][2], bfr[4][2];

  // prologue: tile0 A+B, tile1 B
  STGA(0, 0);
  STGB(0, 0);
  STGB(1, 64);
  VMW2;             // st0 (6 loads) retired; st1.B (2) in flight
  BARR;

#pragma unroll 2
  for (int t = 0; t < 32; ++t) {
    const int d = t & 1;
    // P0
    LDA2(d, 0); LDB2(d);
    if (t < 31) STGA(1 - d, (t + 1) * 64);
    BARR; LGKM0; MM2(0); BARR;
    // P1
    LDA2(d, 1);
    if (t < 30) STGB(d, (t + 2) * 64);
    BARR; LGKM0; MM2(1);
    if (t < 30) { VMW2; } else if (t == 30) { VMW0; }
    BARR;
  }
}

// grid (48, 16), 512 threads. bx<16: Q RoPE; 16-31: K RoPE; 32-47: V^T.
__global__ __launch_bounds__(512, 2)
void gemm_qkv(const u16* __restrict__ A, const u16* __restrict__ Bm,
              u16* __restrict__ qkv, u16* __restrict__ vt) {
  __shared__ __align__(16) u16 S[49152];  // 96 KiB

  const int tid = threadIdx.x;
  // XCD-aware bijective swizzle, col-major logical order: each XCD owns 6
  // consecutive B-panels (weights resident in its L2); A panels hit L3.
  int hwid = blockIdx.y * 48 + blockIdx.x;
  int logical = (hwid & 7) * 96 + (hwid >> 3);
  const int bx = logical >> 4;       // 0..47 (N tile, 128 cols = 1 head)
  const int by = logical & 15;       // 0..15 (M tile, 256 rows)
  const int row0 = by * 256;
  const int col0 = bx * 128;
  const bool vmode = bx >= 32;

  const u16* Ag = A + (size_t)row0 * 2048;
  const u16* Bg = Bm + (size_t)col0 * 2048;

  f32x4 acc[4][4] = {};
  if (vmode) mm_core<true>(Ag, Bg, S, tid, acc);
  else       mm_core<false>(Ag, Bg, S, tid, acc);

  const int lane = tid & 63;
  const int wave = tid >> 6;
  const int quad = lane >> 4;
  const int l15 = lane & 15;
  const int wm = wave >> 1;
  const int wn = wave & 1;

  const int which = bx >> 4;              // 0=q 1=k 2=v
  const int h = bx & 15;
  const int brow = row0 >> 11;
  const int sbase = row0 & 2047;
  const float qs = (which == 0) ? 0.12751744f : 1.0f;  // log2e/sqrt(128)

  // acc -> bf16 tile in S (reuses A region, 64 KB), atom-XOR swizzled
#pragma unroll
  for (int mt = 0; mt < 4; ++mt)
#pragma unroll
    for (int nt = 0; nt < 4; ++nt)
#pragma unroll
      for (int r = 0; r < 4; ++r) {
        int el;
        if (vmode) {  // C^T tile [d=128][s=256], 32 atoms/row
          int dd = wn * 64 + nt * 16 + quad * 4 + r;
          int ss = wm * 64 + mt * 16 + l15;
          el = dd * 256 + (((ss >> 3) ^ (dd & 31)) * 8) + (ss & 7);
        } else {      // tile [s=256][d=128], 16 atoms/row
          int ss = wm * 64 + mt * 16 + quad * 4 + r;
          int dd = wn * 64 + nt * 16 + l15;
          el = ss * 128 + (((dd >> 3) ^ (ss & 15)) * 8) + (dd & 7);
        }
        S[el] = f2bf(acc[mt][nt][r] * qs);
      }
  __syncthreads();

  if (!vmode) {
    const int a = lane & 7;     // d-atom 0..7 (pairs with a+8)
    const int sg = lane >> 3;   // row-in-group
    const float c1 = 0.2076205059304601f;   // log2(10000)/64
    const float c2 = 2.6514961294723187f;   // log2(2*pi)
#pragma unroll
    for (int pass = 0; pass < 4; ++pass) {
      int s_l = pass * 64 + wave * 8 + sg;
      int s2048 = sbase + s_l;
      int sw = s_l & 15;
      bf16x8 x1 = *(const bf16x8_a*)&S[s_l * 128 + ((a ^ sw) * 8)];
      bf16x8 x2 = *(const bf16x8_a*)&S[s_l * 128 + (((a + 8) ^ sw) * 8)];
      u16 o1[8], o2[8];
#pragma unroll
      for (int e = 0; e < 8; ++e) {
        float j = (float)(a * 8 + e);
        float rev = (float)s2048 * __builtin_amdgcn_exp2f(-c1 * j - c2);
        rev = __builtin_amdgcn_fractf(rev);
        float sn = __builtin_amdgcn_sinf(rev);
        float cs = __builtin_amdgcn_cosf(rev);
        float v1 = (float)x1[e], v2 = (float)x2[e];
        o1[e] = f2bf(v1 * cs - v2 * sn);
        o2[e] = f2bf(v2 * cs + v1 * sn);
      }
      size_t base =
          ((((size_t)which * 2 + brow) * 16 + h) * SEQ + s2048) * HD + a * 8;
      *(uint4_a*)&qkv[base] = *(uint4*)o1;
      *(uint4_a*)&qkv[base + 64] = *(uint4*)o2;
    }
  } else {  // V: transposed copy-out, vt[b,h,d,s]
    const int d_part = tid >> 4;        // 0..31
    const int a0 = tid & 15;            // atom 0..15 (+16 for second)
#pragma unroll
    for (int pass = 0; pass < 4; ++pass) {
      int d_l = pass * 32 + d_part;     // 0..127
      int dw = d_l & 31;
      size_t rb = (((size_t)brow * 16 + h) * HD + d_l) * SEQ + sbase;
#pragma unroll
      for (int g = 0; g < 2; ++g) {
        int a2 = a0 + g * 16;
        bf16x8 y = *(const bf16x8_a*)&S[d_l * 256 + ((a2 ^ dw) * 8)];
        *(uint4_a*)&vt[rb + a2 * 8] = *(uint4_a*)&y;
      }
    }
  }
}

// ---------------- output GEMM: same core, fp32 + bias epilogue -------------
// grid (16, 16) = 256 blocks = exactly 1 CU-round.
__global__ __launch_bounds__(512, 2)
void gemm_out(const u16* __restrict__ A, const u16* __restrict__ Bm,
              float* __restrict__ C, const float* __restrict__ bias) {
  __shared__ __align__(16) u16 S[49152];  // 96 KiB

  const int tid = threadIdx.x;
  int hwid = blockIdx.y * 16 + blockIdx.x;
  int logical = (hwid & 7) * 32 + (hwid >> 3);
  const int bx = logical >> 4;       // 0..15 (N tile)
  const int by = logical & 15;       // 0..15 (M tile)
  const int row0 = by * 256;
  const int col0 = bx * 128;

  const u16* Ag = A + (size_t)row0 * 2048;
  const u16* Bg = Bm + (size_t)col0 * 2048;

  f32x4 acc[4][4] = {};
  mm_core<false>(Ag, Bg, S, tid, acc);

  const int lane = tid & 63;
  const int wave = tid >> 6;
  const int quad = lane >> 4;
  const int l15 = lane & 15;
  const int wm = wave >> 1;
  const int wn = wave & 1;

#pragma unroll
  for (int nt = 0; nt < 4; ++nt) {
    int d = col0 + wn * 64 + nt * 16 + l15;
    float bv = bias[d];
#pragma unroll
    for (int mt = 0; mt < 4; ++mt) {
#pragma unroll
      for (int r = 0; r < 4; ++r) {
        int row = row0 + wm * 64 + mt * 16 + quad * 4 + r;
        C[(size_t)row * DMODEL + d] = acc[mt][nt][r] + bv;
      }
    }
  }
}

// ---------------- Flash attention (R7: KV dbuf + counted vmcnt) ------------
// grid (S/128, B*H), 4 waves; wave owns 32 Q rows (2 m-tiles).
// Per tile t: compute on buf[t&1]; BARR; stage(t+2)->buf[t&1]; vmcnt(8)
// (stage(t+1) retired, stage(t+2) in flight); BARR. Staging latency hides
// under one full compute phase. setprio(1) around both MFMA clusters.
__global__ __launch_bounds__(256, 2)
void attn_kernel(const u16* __restrict__ qkv, const u16* __restrict__ vt,
                 u16* __restrict__ attn_out) {
  __shared__ __align__(16) u16 Kl[2][64 * 128];   // [kv][hd] swizzled atoms
  __shared__ __align__(16) u16 Vl[2][128 * 64];   // [d][kv] swizzled atoms
  __shared__ __align__(16) u16 Pl[4][32 * 64];    // per-wave [q][kv] swizzled

  const int tid = threadIdx.x;
  const int lane = tid & 63;
  const int wave = tid >> 6;
  const int quad = lane >> 4;
  const int l15 = lane & 15;
  const int q0 = blockIdx.x * 128;
  const int bh = blockIdx.y;
  const size_t SD = (size_t)SEQ * HD;

  const u16* Q = qkv + (size_t)bh * SD;          // which=0 (pre-scaled)
  const u16* Kg = qkv + (size_t)(32 + bh) * SD;  // which=1
  const u16* Vg = vt + (size_t)bh * SD;          // [d][s]

  // ones A-fragment in registers: row m=0 (lanes l15==0) = 1.0, else 0.
  bf16x8 onesf;
#pragma unroll
  for (int e = 0; e < 8; ++e)
    onesf[e] = (l15 == 0) ? (__bf16)1.0f : (__bf16)0.0f;

  // Q fragments first: oldest in the vmcnt FIFO, retired before first use.
  bf16x8 qf[2][4];  // Q[q=mt*16+l15][hd=c*32+quad*8+j]
#pragma unroll
  for (int mt = 0; mt < 2; ++mt) {
    int qrow = q0 + wave * 32 + mt * 16 + l15;
#pragma unroll
    for (int c = 0; c < 4; ++c)
      qf[mt][c] = *(const bf16x8*)(Q + (size_t)qrow * HD + c * 32 + quad * 8);
  }

  f32x4 of[9][2] = {};   // of[0..7]: O^T[d][q]; of[8] row0: l (ones frag)
  u16* pw = &Pl[wave][0];

  // stage one 64-wide KV tile into buffer `buf` (8 loads/thread)
  auto stage = [&](int tile, int buf) {
    int kv0 = tile * 64;
#pragma unroll
    for (int j = 0; j < 4; ++j) {
      int idx = (wave * 4 + j) * 64 + lane;
      {  // K: 64 rows x 16 atoms, swizzle ^(row&15)
        int r = idx >> 4, cs = idx & 15;
        int cc = cs ^ (r & 15);
        load_lds16(Kg + (size_t)(kv0 + r) * HD + cc * 8, &Kl[buf][idx * 8]);
      }
      {  // VT: 128 rows x 8 atoms, swizzle ^(row&7)
        int r = idx >> 3, cs = idx & 7;
        int cc = cs ^ (r & 7);
        load_lds16(Vg + (size_t)r * SEQ + kv0 + cc * 8, &Vl[buf][idx * 8]);
      }
    }
  };

  // prologue: tiles 0 and 1; vmcnt(8) = stage(0) retired (stage(1) in flight)
  stage(0, 0);
  stage(1, 1);
  VMW8;
  BARR;

#pragma unroll 2
  for (int t = 0; t < 32; ++t) {
    const u16* Kb = Kl[t & 1];
    const u16* Vb = Vl[t & 1];

    // S^T tiles: sc[nt][mt], rows kv=nt*16+quad*4+r, cols q=mt*16+l15
    f32x4 sc[4][2] = {};
    __builtin_amdgcn_s_setprio(1);
#pragma unroll
    for (int c = 0; c < 4; ++c) {
      bf16x8 kf[4];
#pragma unroll
      for (int nt = 0; nt < 4; ++nt)
        kf[nt] = *(const bf16x8*)&Kb[((nt * 16 + l15) * 16 +
                                      ((c * 4 + quad) ^ l15)) * 8];
#pragma unroll
      for (int nt = 0; nt < 4; ++nt)
#pragma unroll
        for (int mt = 0; mt < 2; ++mt)
          sc[nt][mt] = __builtin_amdgcn_mfma_f32_16x16x32_bf16(
              kf[nt], qf[mt][c], sc[nt][mt], 0, 0, 0);
    }
    __builtin_amdgcn_s_setprio(0);

    // P = exp2(sc); truncate-pack via v_perm; b64 writes (wave-private Pl)
#pragma unroll
    for (int nt = 0; nt < 4; ++nt) {
#pragma unroll
      for (int mt = 0; mt < 2; ++mt) {
        float p0 = __builtin_amdgcn_exp2f(sc[nt][mt][0]);
        float p1 = __builtin_amdgcn_exp2f(sc[nt][mt][1]);
        float p2 = __builtin_amdgcn_exp2f(sc[nt][mt][2]);
        float p3 = __builtin_amdgcn_exp2f(sc[nt][mt][3]);
        u32 lo = __builtin_amdgcn_perm(__float_as_uint(p1),
                                       __float_as_uint(p0), 0x07060302u);
        u32 hi = __builtin_amdgcn_perm(__float_as_uint(p3),
                                       __float_as_uint(p2), 0x07060302u);
        int row = mt * 16 + l15;
        int a = nt * 2 + (quad >> 1);
        int idx16 = (row * 8 + (a ^ (l15 & 7))) * 8 + (quad & 1) * 4;
        uint2 pk; pk.x = lo; pk.y = hi;
        *(uint2_a*)&pw[idx16] = pk;
      }
    }

    // O^T += V^T.P ; dt=8 uses the register ones-frag -> row sums (l)
    __builtin_amdgcn_s_setprio(1);
#pragma unroll
    for (int c = 0; c < 2; ++c) {
      bf16x8 pf[2];
#pragma unroll
      for (int mt = 0; mt < 2; ++mt)
        pf[mt] = *(const bf16x8_a*)&pw[((mt * 16 + l15) * 8 +
                                        ((c * 4 + quad) ^ (l15 & 7))) * 8];
#pragma unroll
      for (int dt = 0; dt < 9; ++dt) {
        bf16x8 vf = (dt < 8)
                        ? *(const bf16x8*)&Vb[((dt * 16 + l15) * 8 +
                                               ((c * 4 + quad) ^ (l15 & 7))) * 8]
                        : onesf;
#pragma unroll
        for (int mt = 0; mt < 2; ++mt)
          of[dt][mt] = __builtin_amdgcn_mfma_f32_16x16x32_bf16(
              vf, pf[mt], of[dt][mt], 0, 0, 0);
      }
    }
    __builtin_amdgcn_s_setprio(0);

    // all waves done reading buf[t&1]; restage it for tile t+2
    BARR;
    if (t < 30) {
      stage(t + 2, t & 1);
      VMW8;              // stage(t+1) retired; stage(t+2) stays in flight
    } else {
      VMW0;              // tail: drain (covers stage(31) at t=30)
    }
    BARR;
  }

  // l lives at of[8][mt][0] on quad-0 lanes (C row 0); broadcast by shfl.
  const int b = bh >> 4, h = bh & 15;
#pragma unroll
  for (int mt = 0; mt < 2; ++mt) {
    float lsum = __shfl(of[8][mt][0], l15, 64);
    float inv = 1.f / lsum;
    int s = q0 + wave * 32 + mt * 16 + l15;
    size_t rowb = ((size_t)b * SEQ + s) * DMODEL + h * HD;
#pragma unroll
    for (int dt = 0; dt < 8; ++dt) {
      ushort4 ov;
      ov.x = f2bf(of[dt][mt][0] * inv);
      ov.y = f2bf(of[dt][mt][1] * inv);
      ov.z = f2bf(of[dt][mt][2] * inv);
      ov.w = f2bf(of[dt][mt][3] * inv);
      *(ushort4*)&attn_out[rowb + dt * 16 + quad * 4] = ov;
    }
  }
}

extern "C" void kernel_launch(void* const* d_in, const int* in_sizes, int n_in,
                              void* d_out, int out_size, void* d_ws,
                              size_t ws_size, hipStream_t stream) {
  const float* x = (const float*)d_in[0];
  const float* Wq = (const float*)d_in[1];
  const float* Wk = (const float*)d_in[2];
  const float* Wv = (const float*)d_in[3];
  const float* Wo = (const float*)d_in[4];
  const float* bo = (const float*)d_in[5];
  float* out = (float*)d_out;

  char* ws = (char*)d_ws;
  u16* xb = (u16*)(ws);                              // 16 MiB
  u16* wqkv = (u16*)(ws + (size_t)(16 << 20));       // 24 MiB
  u16* wob = (u16*)(ws + (size_t)(40 << 20));        // 8 MiB
  u16* qkv = (u16*)(ws + (size_t)(48 << 20));        // 48 MiB: Q | K | vt
  u16* vt = qkv + (size_t)2 * 8388608;               // vt in the V slot
  u16* attn = xb;                                    // reuse after GEMMs

  // fp32 -> bf16 (one fused launch)
  conv_all<<<24576, 256, 0, stream>>>(x, Wq, Wk, Wv, Wo, xb, wqkv, wob);

  // Q,K (fused RoPE) + V^T: 256x128 tiles, 768 blocks = 3 exact CU-rounds
  gemm_qkv<<<dim3(48, 16), 512, 0, stream>>>(xb, wqkv, qkv, vt);
  // flash attention
  attn_kernel<<<dim3(16, 32), 256, 0, stream>>>(qkv, vt, attn);
  // out = attn @ wob^T + bo: 256x128 tiles, 256 blocks = 1 exact CU-round
  gemm_out<<<dim3(16, 16), 512, 0, stream>>>(attn, wob, out, bo);
}

// Round 4
// 356.475 us; speedup vs baseline: 1.0532x; 1.0069x over previous
//
#include <hip/hip_runtime.h>
#include <stdint.h>

// MultiHeadAttention: B=2, S=2048, D=2048, H=16, Dh=128, fp32 in/out.
// R9: mm_core gets TRIPLE-buffered A and B (LDS 144 KiB, 1 block/CU).
//     R8's 2-phase schedule only covered ~1 phase (~300cy) of load latency
//     (vmcnt waited on loads issued the same K-tile) -> per-K-tile stall.
//     Now tile t+2 is staged during tile t; vmcnt(6) at end of t waits on
//     loads issued at t-1 (~600-900cy cover = full HBM latency). Grid stays
//     768 = 3 exact CU-rounds (gemm_qkv) / 256 = 1 round (gemm_out).
//     attn_kernel / conv_all unchanged (R7).

#define SEQ 2048
#define HD 128
#define DMODEL 2048

typedef __bf16 bf16x8 __attribute__((ext_vector_type(8)));
typedef float f32x4 __attribute__((ext_vector_type(4)));
typedef unsigned short u16;
typedef unsigned int u32;

typedef bf16x8 __attribute__((may_alias)) bf16x8_a;
typedef uint2 __attribute__((may_alias)) uint2_a;
typedef uint4 __attribute__((may_alias)) uint4_a;

__device__ __forceinline__ u16 f2bf(float f) {
  unsigned int u = __float_as_uint(f);
  u += 0x7fff + ((u >> 16) & 1);   // RNE; inputs are finite normals
  return (u16)(u >> 16);
}

typedef __attribute__((address_space(1))) void* gas_t;
typedef __attribute__((address_space(3))) void* las_t;
// async global->LDS, 16B/lane. LDS dest must be uniform base + lane*16.
__device__ __forceinline__ void load_lds16(const void* g, void* l) {
  __builtin_amdgcn_global_load_lds((gas_t)(uintptr_t)g,
                                   (las_t)(uint32_t)(uintptr_t)l, 16, 0, 0);
}

// ---------------- fp32 -> bf16 convert (all 5 tensors, one launch) ---------
__global__ void conv_all(const float* __restrict__ x,
                         const float* __restrict__ wq,
                         const float* __restrict__ wk,
                         const float* __restrict__ wv,
                         const float* __restrict__ wo,
                         u16* __restrict__ xb, u16* __restrict__ wqkv,
                         u16* __restrict__ wob) {
  int i = blockIdx.x * 256 + threadIdx.x;  // float4 index
  const float* src;
  u16* dst;
  int off;
  if (i < 2097152) { src = x; dst = xb; off = i; }
  else if (i < 3145728) { src = wq; dst = wqkv; off = i - 2097152; }
  else if (i < 4194304) { src = wk; dst = wqkv + 4194304; off = i - 3145728; }
  else if (i < 5242880) { src = wv; dst = wqkv + 8388608; off = i - 4194304; }
  else { src = wo; dst = wob; off = i - 5242880; }
  float4 v = ((const float4*)src)[off];
  ushort4 o;
  o.x = f2bf(v.x); o.y = f2bf(v.y); o.z = f2bf(v.z); o.w = f2bf(v.w);
  ((ushort4*)dst)[off] = o;
}

// ============== 256x128-tile 2-phase, TRIPLE-buffered GEMM core ============
// 8 waves 4M x 2N (wave tile 64x64, acc[4][4]); BK=64, K=2048 (32 K-tiles).
// LDS 144 KiB: A[3][256x64] (96 KB) + B[3][128x64] (48 KB).
// Iteration t (CUR = t%3 compile-time via 3-step unroll):
//  P0: ds_read A(CUR,mt01)+B(CUR,all->regs); issue stage A(t+2)->(t+2)%3;
//      BARR; lgkmcnt(0); 16 MFMA; BARR.
//  P1: ds_read A(CUR,mt23); issue stage B(t+2); BARR; lgkmcnt(0); 16 MFMA;
//      vmcnt(6) [retires A(t+1),B(t+1) issued at t-1 = 2-3 phases cover;
//      leaves A(t+2),B(t+2) in flight]; BARR.
// Deadness: A[(t+2)%3] last ds_read at t-1, drained by each wave's own
// lgkmcnt(0) >=2 barriers before the overwrite issues. Same for B.

#define BARR asm volatile("s_barrier" ::: "memory")
#define LGKM0 asm volatile("s_waitcnt lgkmcnt(0)" ::: "memory")
#define VMW6 asm volatile("s_waitcnt vmcnt(6)" ::: "memory")
#define VMW8 asm volatile("s_waitcnt vmcnt(8)" ::: "memory")
#define VMW0 asm volatile("s_waitcnt vmcnt(0)" ::: "memory")

#define STGA(D, KOFF) do {                                                  \
    const u16* ga_ = Ag + (KOFF);                                           \
    u16* la_ = S + (D) * 16384;                                             \
    load_lds16(ga_ + off[0], la_ + tid * 8);                                \
    load_lds16(ga_ + off[1], la_ + (tid + 512) * 8);                        \
    load_lds16(ga_ + off[2], la_ + (tid + 1024) * 8);                       \
    load_lds16(ga_ + off[3], la_ + (tid + 1536) * 8);                       \
  } while (0)

#define STGB(D, KOFF) do {                                                  \
    const u16* gb_ = Bg + (KOFF);                                           \
    u16* lb_ = S + 49152 + (D) * 8192;                                      \
    load_lds16(gb_ + off[0], lb_ + tid * 8);                                \
    load_lds16(gb_ + off[1], lb_ + (tid + 512) * 8);                        \
  } while (0)

#define LDA2(D, MH) do {                                                    \
    const u16* ab_ = S + (D) * 16384;                                       \
    _Pragma("unroll") for (int mt_ = 0; mt_ < 2; ++mt_) {                   \
      int rA_ = wm * 64 + ((MH) * 2 + mt_) * 16 + l15;                      \
      int sw_ = rA_ & 7;                                                    \
      af[mt_][0] = *(const bf16x8_a*)(ab_ + (rA_ * 8 + (quad ^ sw_)) * 8);  \
      af[mt_][1] = *(const bf16x8_a*)(ab_ + (rA_ * 8 + ((4 + quad) ^ sw_)) * 8); \
    } } while (0)

#define LDB2(D) do {                                                        \
    const u16* bb_ = S + 49152 + (D) * 8192;                                \
    _Pragma("unroll") for (int nt_ = 0; nt_ < 4; ++nt_) {                   \
      int rB_ = wn * 64 + nt_ * 16 + l15;                                   \
      int sw_ = rB_ & 7;                                                    \
      bfr[nt_][0] = *(const bf16x8_a*)(bb_ + (rB_ * 8 + (quad ^ sw_)) * 8); \
      bfr[nt_][1] = *(const bf16x8_a*)(bb_ + (rB_ * 8 + ((4 + quad) ^ sw_)) * 8); \
    } } while (0)

#define MM2(MH) do {                                                        \
    __builtin_amdgcn_s_setprio(1);                                          \
    _Pragma("unroll") for (int c_ = 0; c_ < 2; ++c_)                        \
      _Pragma("unroll") for (int mt_ = 0; mt_ < 2; ++mt_)                   \
        _Pragma("unroll") for (int nt_ = 0; nt_ < 4; ++nt_) {               \
          if (VM)                                                           \
            acc[(MH) * 2 + mt_][nt_] =                                      \
                __builtin_amdgcn_mfma_f32_16x16x32_bf16(                    \
                    bfr[nt_][c_], af[mt_][c_],                              \
                    acc[(MH) * 2 + mt_][nt_], 0, 0, 0);                     \
          else                                                              \
            acc[(MH) * 2 + mt_][nt_] =                                      \
                __builtin_amdgcn_mfma_f32_16x16x32_bf16(                    \
                    af[mt_][c_], bfr[nt_][c_],                              \
                    acc[(MH) * 2 + mt_][nt_], 0, 0, 0);                     \
        }                                                                   \
    __builtin_amdgcn_s_setprio(0);                                          \
  } while (0)

// one steady-state K-tile; CUR/NX2 are compile-time (3-step unroll)
#define STEP3(T, CUR, NX2) do {                                             \
    LDA2(CUR, 0); LDB2(CUR);                                                \
    STGA(NX2, ((T) + 2) * 64);                                              \
    BARR; LGKM0; MM2(0); BARR;                                              \
    LDA2(CUR, 1);                                                           \
    STGB(NX2, ((T) + 2) * 64);                                              \
    BARR; LGKM0; MM2(1); VMW6; BARR;                                        \
  } while (0)

template <bool VM>
__device__ __forceinline__ void mm_core(const u16* __restrict__ Ag,
                                        const u16* __restrict__ Bg,
                                        u16* __restrict__ S, int tid,
                                        f32x4 acc[4][4]) {
  const int lane = tid & 63;
  const int wave = tid >> 6;
  const int quad = lane >> 4;
  const int l15 = lane & 15;
  const int wm = wave >> 1;
  const int wn = wave & 1;

  // staging offsets: atom idx = tid + j*512; row = idx>>3 (stride K=2048);
  // source k8 pre-swizzled by ^(row&7); LDS dest linear (both-sides rule).
  u32 off[4];
#pragma unroll
  for (int j = 0; j < 4; ++j) {
    int idx = tid + j * 512;
    int r = idx >> 3;
    off[j] = (u32)r * 2048u + (u32)(((idx & 7) ^ (r & 7)) * 8);
  }

  bf16x8 af[2][2], bfr[4][2];

  // prologue: tiles 0 and 1 (A+B each); retire tile0, leave tile1 in flight
  STGA(0, 0);
  STGB(0, 0);
  STGA(1, 64);
  STGB(1, 64);
  VMW6;             // A0,B0 retired; A1,B1 (6 loads) in flight
  BARR;

  // t = 0..29 in groups of 3 (tt = 0,3,...,27 so tt % 3 == 0 always)
#pragma unroll 1
  for (int tt = 0; tt < 30; tt += 3) {
    STEP3(tt,     0, 2);
    STEP3(tt + 1, 1, 0);
    STEP3(tt + 2, 2, 1);
  }

  // t = 30 (CUR=0): no staging; drain everything for t=31
  LDA2(0, 0); LDB2(0);
  BARR; LGKM0; MM2(0); BARR;
  LDA2(0, 1);
  BARR; LGKM0; MM2(1); VMW0; BARR;
  // t = 31 (CUR=1)
  LDA2(1, 0); LDB2(1);
  BARR; LGKM0; MM2(0); BARR;
  LDA2(1, 1);
  BARR; LGKM0; MM2(1); BARR;
}

// grid (48, 16), 512 threads. bx<16: Q RoPE; 16-31: K RoPE; 32-47: V^T.
__global__ __launch_bounds__(512, 2)
void gemm_qkv(const u16* __restrict__ A, const u16* __restrict__ Bm,
              u16* __restrict__ qkv, u16* __restrict__ vt) {
  __shared__ __align__(16) u16 S[73728];  // 144 KiB: A[3][16384]+B[3][8192]

  const int tid = threadIdx.x;
  // XCD-aware bijective swizzle, col-major logical order: each XCD owns 6
  // consecutive B-panels (weights resident in its L2); A panels hit L3.
  int hwid = blockIdx.y * 48 + blockIdx.x;
  int logical = (hwid & 7) * 96 + (hwid >> 3);
  const int bx = logical >> 4;       // 0..47 (N tile, 128 cols = 1 head)
  const int by = logical & 15;       // 0..15 (M tile, 256 rows)
  const int row0 = by * 256;
  const int col0 = bx * 128;
  const bool vmode = bx >= 32;

  const u16* Ag = A + (size_t)row0 * 2048;
  const u16* Bg = Bm + (size_t)col0 * 2048;

  f32x4 acc[4][4] = {};
  if (vmode) mm_core<true>(Ag, Bg, S, tid, acc);
  else       mm_core<false>(Ag, Bg, S, tid, acc);

  const int lane = tid & 63;
  const int wave = tid >> 6;
  const int quad = lane >> 4;
  const int l15 = lane & 15;
  const int wm = wave >> 1;
  const int wn = wave & 1;

  const int which = bx >> 4;              // 0=q 1=k 2=v
  const int h = bx & 15;
  const int brow = row0 >> 11;
  const int sbase = row0 & 2047;
  const float qs = (which == 0) ? 0.12751744f : 1.0f;  // log2e/sqrt(128)

  // acc -> bf16 tile in S (reuses A region), atom-XOR swizzled
#pragma unroll
  for (int mt = 0; mt < 4; ++mt)
#pragma unroll
    for (int nt = 0; nt < 4; ++nt)
#pragma unroll
      for (int r = 0; r < 4; ++r) {
        int el;
        if (vmode) {  // C^T tile [d=128][s=256], 32 atoms/row
          int dd = wn * 64 + nt * 16 + quad * 4 + r;
          int ss = wm * 64 + mt * 16 + l15;
          el = dd * 256 + (((ss >> 3) ^ (dd & 31)) * 8) + (ss & 7);
        } else {      // tile [s=256][d=128], 16 atoms/row
          int ss = wm * 64 + mt * 16 + quad * 4 + r;
          int dd = wn * 64 + nt * 16 + l15;
          el = ss * 128 + (((dd >> 3) ^ (ss & 15)) * 8) + (dd & 7);
        }
        S[el] = f2bf(acc[mt][nt][r] * qs);
      }
  __syncthreads();

  if (!vmode) {
    const int a = lane & 7;     // d-atom 0..7 (pairs with a+8)
    const int sg = lane >> 3;   // row-in-group
    const float c1 = 0.2076205059304601f;   // log2(10000)/64
    const float c2 = 2.6514961294723187f;   // log2(2*pi)
#pragma unroll
    for (int pass = 0; pass < 4; ++pass) {
      int s_l = pass * 64 + wave * 8 + sg;
      int s2048 = sbase + s_l;
      int sw = s_l & 15;
      bf16x8 x1 = *(const bf16x8_a*)&S[s_l * 128 + ((a ^ sw) * 8)];
      bf16x8 x2 = *(const bf16x8_a*)&S[s_l * 128 + (((a + 8) ^ sw) * 8)];
      u16 o1[8], o2[8];
#pragma unroll
      for (int e = 0; e < 8; ++e) {
        float j = (float)(a * 8 + e);
        float rev = (float)s2048 * __builtin_amdgcn_exp2f(-c1 * j - c2);
        rev = __builtin_amdgcn_fractf(rev);
        float sn = __builtin_amdgcn_sinf(rev);
        float cs = __builtin_amdgcn_cosf(rev);
        float v1 = (float)x1[e], v2 = (float)x2[e];
        o1[e] = f2bf(v1 * cs - v2 * sn);
        o2[e] = f2bf(v2 * cs + v1 * sn);
      }
      size_t base =
          ((((size_t)which * 2 + brow) * 16 + h) * SEQ + s2048) * HD + a * 8;
      *(uint4_a*)&qkv[base] = *(uint4*)o1;
      *(uint4_a*)&qkv[base + 64] = *(uint4*)o2;
    }
  } else {  // V: transposed copy-out, vt[b,h,d,s]
    const int d_part = tid >> 4;        // 0..31
    const int a0 = tid & 15;            // atom 0..15 (+16 for second)
#pragma unroll
    for (int pass = 0; pass < 4; ++pass) {
      int d_l = pass * 32 + d_part;     // 0..127
      int dw = d_l & 31;
      size_t rb = (((size_t)brow * 16 + h) * HD + d_l) * SEQ + sbase;
#pragma unroll
      for (int g = 0; g < 2; ++g) {
        int a2 = a0 + g * 16;
        bf16x8 y = *(const bf16x8_a*)&S[d_l * 256 + ((a2 ^ dw) * 8)];
        *(uint4_a*)&vt[rb + a2 * 8] = *(uint4_a*)&y;
      }
    }
  }
}

// ---------------- output GEMM: same core, fp32 + bias epilogue -------------
// grid (16, 16) = 256 blocks = exactly 1 CU-round.
__global__ __launch_bounds__(512, 2)
void gemm_out(const u16* __restrict__ A, const u16* __restrict__ Bm,
              float* __restrict__ C, const float* __restrict__ bias) {
  __shared__ __align__(16) u16 S[73728];  // 144 KiB

  const int tid = threadIdx.x;
  int hwid = blockIdx.y * 16 + blockIdx.x;
  int logical = (hwid & 7) * 32 + (hwid >> 3);
  const int bx = logical >> 4;       // 0..15 (N tile)
  const int by = logical & 15;       // 0..15 (M tile)
  const int row0 = by * 256;
  const int col0 = bx * 128;

  const u16* Ag = A + (size_t)row0 * 2048;
  const u16* Bg = Bm + (size_t)col0 * 2048;

  f32x4 acc[4][4] = {};
  mm_core<false>(Ag, Bg, S, tid, acc);

  const int lane = tid & 63;
  const int wave = tid >> 6;
  const int quad = lane >> 4;
  const int l15 = lane & 15;
  const int wm = wave >> 1;
  const int wn = wave & 1;

#pragma unroll
  for (int nt = 0; nt < 4; ++nt) {
    int d = col0 + wn * 64 + nt * 16 + l15;
    float bv = bias[d];
#pragma unroll
    for (int mt = 0; mt < 4; ++mt) {
#pragma unroll
      for (int r = 0; r < 4; ++r) {
        int row = row0 + wm * 64 + mt * 16 + quad * 4 + r;
        C[(size_t)row * DMODEL + d] = acc[mt][nt][r] + bv;
      }
    }
  }
}

// ---------------- Flash attention (R7: KV dbuf + counted vmcnt) ------------
// grid (S/128, B*H), 4 waves; wave owns 32 Q rows (2 m-tiles).
// Per tile t: compute on buf[t&1]; BARR; stage(t+2)->buf[t&1]; vmcnt(8)
// (stage(t+1) retired, stage(t+2) in flight); BARR. Staging latency hides
// under one full compute phase. setprio(1) around both MFMA clusters.
__global__ __launch_bounds__(256, 2)
void attn_kernel(const u16* __restrict__ qkv, const u16* __restrict__ vt,
                 u16* __restrict__ attn_out) {
  __shared__ __align__(16) u16 Kl[2][64 * 128];   // [kv][hd] swizzled atoms
  __shared__ __align__(16) u16 Vl[2][128 * 64];   // [d][kv] swizzled atoms
  __shared__ __align__(16) u16 Pl[4][32 * 64];    // per-wave [q][kv] swizzled

  const int tid = threadIdx.x;
  const int lane = tid & 63;
  const int wave = tid >> 6;
  const int quad = lane >> 4;
  const int l15 = lane & 15;
  const int q0 = blockIdx.x * 128;
  const int bh = blockIdx.y;
  const size_t SD = (size_t)SEQ * HD;

  const u16* Q = qkv + (size_t)bh * SD;          // which=0 (pre-scaled)
  const u16* Kg = qkv + (size_t)(32 + bh) * SD;  // which=1
  const u16* Vg = vt + (size_t)bh * SD;          // [d][s]

  // ones A-fragment in registers: row m=0 (lanes l15==0) = 1.0, else 0.
  bf16x8 onesf;
#pragma unroll
  for (int e = 0; e < 8; ++e)
    onesf[e] = (l15 == 0) ? (__bf16)1.0f : (__bf16)0.0f;

  // Q fragments first: oldest in the vmcnt FIFO, retired before first use.
  bf16x8 qf[2][4];  // Q[q=mt*16+l15][hd=c*32+quad*8+j]
#pragma unroll
  for (int mt = 0; mt < 2; ++mt) {
    int qrow = q0 + wave * 32 + mt * 16 + l15;
#pragma unroll
    for (int c = 0; c < 4; ++c)
      qf[mt][c] = *(const bf16x8*)(Q + (size_t)qrow * HD + c * 32 + quad * 8);
  }

  f32x4 of[9][2] = {};   // of[0..7]: O^T[d][q]; of[8] row0: l (ones frag)
  u16* pw = &Pl[wave][0];

  // stage one 64-wide KV tile into buffer `buf` (8 loads/thread)
  auto stage = [&](int tile, int buf) {
    int kv0 = tile * 64;
#pragma unroll
    for (int j = 0; j < 4; ++j) {
      int idx = (wave * 4 + j) * 64 + lane;
      {  // K: 64 rows x 16 atoms, swizzle ^(row&15)
        int r = idx >> 4, cs = idx & 15;
        int cc = cs ^ (r & 15);
        load_lds16(Kg + (size_t)(kv0 + r) * HD + cc * 8, &Kl[buf][idx * 8]);
      }
      {  // VT: 128 rows x 8 atoms, swizzle ^(row&7)
        int r = idx >> 3, cs = idx & 7;
        int cc = cs ^ (r & 7);
        load_lds16(Vg + (size_t)r * SEQ + kv0 + cc * 8, &Vl[buf][idx * 8]);
      }
    }
  };

  // prologue: tiles 0 and 1; vmcnt(8) = stage(0) retired (stage(1) in flight)
  stage(0, 0);
  stage(1, 1);
  VMW8;
  BARR;

#pragma unroll 2
  for (int t = 0; t < 32; ++t) {
    const u16* Kb = Kl[t & 1];
    const u16* Vb = Vl[t & 1];

    // S^T tiles: sc[nt][mt], rows kv=nt*16+quad*4+r, cols q=mt*16+l15
    f32x4 sc[4][2] = {};
    __builtin_amdgcn_s_setprio(1);
#pragma unroll
    for (int c = 0; c < 4; ++c) {
      bf16x8 kf[4];
#pragma unroll
      for (int nt = 0; nt < 4; ++nt)
        kf[nt] = *(const bf16x8*)&Kb[((nt * 16 + l15) * 16 +
                                      ((c * 4 + quad) ^ l15)) * 8];
#pragma unroll
      for (int nt = 0; nt < 4; ++nt)
#pragma unroll
        for (int mt = 0; mt < 2; ++mt)
          sc[nt][mt] = __builtin_amdgcn_mfma_f32_16x16x32_bf16(
              kf[nt], qf[mt][c], sc[nt][mt], 0, 0, 0);
    }
    __builtin_amdgcn_s_setprio(0);

    // P = exp2(sc); truncate-pack via v_perm; b64 writes (wave-private Pl)
#pragma unroll
    for (int nt = 0; nt < 4; ++nt) {
#pragma unroll
      for (int mt = 0; mt < 2; ++mt) {
        float p0 = __builtin_amdgcn_exp2f(sc[nt][mt][0]);
        float p1 = __builtin_amdgcn_exp2f(sc[nt][mt][1]);
        float p2 = __builtin_amdgcn_exp2f(sc[nt][mt][2]);
        float p3 = __builtin_amdgcn_exp2f(sc[nt][mt][3]);
        u32 lo = __builtin_amdgcn_perm(__float_as_uint(p1),
                                       __float_as_uint(p0), 0x07060302u);
        u32 hi = __builtin_amdgcn_perm(__float_as_uint(p3),
                                       __float_as_uint(p2), 0x07060302u);
        int row = mt * 16 + l15;
        int a = nt * 2 + (quad >> 1);
        int idx16 = (row * 8 + (a ^ (l15 & 7))) * 8 + (quad & 1) * 4;
        uint2 pk; pk.x = lo; pk.y = hi;
        *(uint2_a*)&pw[idx16] = pk;
      }
    }

    // O^T += V^T.P ; dt=8 uses the register ones-frag -> row sums (l)
    __builtin_amdgcn_s_setprio(1);
#pragma unroll
    for (int c = 0; c < 2; ++c) {
      bf16x8 pf[2];
#pragma unroll
      for (int mt = 0; mt < 2; ++mt)
        pf[mt] = *(const bf16x8_a*)&pw[((mt * 16 + l15) * 8 +
                                        ((c * 4 + quad) ^ (l15 & 7))) * 8];
#pragma unroll
      for (int dt = 0; dt < 9; ++dt) {
        bf16x8 vf = (dt < 8)
                        ? *(const bf16x8*)&Vb[((dt * 16 + l15) * 8 +
                                               ((c * 4 + quad) ^ (l15 & 7))) * 8]
                        : onesf;
#pragma unroll
        for (int mt = 0; mt < 2; ++mt)
          of[dt][mt] = __builtin_amdgcn_mfma_f32_16x16x32_bf16(
              vf, pf[mt], of[dt][mt], 0, 0, 0);
      }
    }
    __builtin_amdgcn_s_setprio(0);

    // all waves done reading buf[t&1]; restage it for tile t+2
    BARR;
    if (t < 30) {
      stage(t + 2, t & 1);
      VMW8;              // stage(t+1) retired; stage(t+2) stays in flight
    } else {
      VMW0;              // tail: drain (covers stage(31) at t=30)
    }
    BARR;
  }

  // l lives at of[8][mt][0] on quad-0 lanes (C row 0); broadcast by shfl.
  const int b = bh >> 4, h = bh & 15;
#pragma unroll
  for (int mt = 0; mt < 2; ++mt) {
    float lsum = __shfl(of[8][mt][0], l15, 64);
    float inv = 1.f / lsum;
    int s = q0 + wave * 32 + mt * 16 + l15;
    size_t rowb = ((size_t)b * SEQ + s) * DMODEL + h * HD;
#pragma unroll
    for (int dt = 0; dt < 8; ++dt) {
      ushort4 ov;
      ov.x = f2bf(of[dt][mt][0] * inv);
      ov.y = f2bf(of[dt][mt][1] * inv);
      ov.z = f2bf(of[dt][mt][2] * inv);
      ov.w = f2bf(of[dt][mt][3] * inv);
      *(ushort4*)&attn_out[rowb + dt * 16 + quad * 4] = ov;
    }
  }
}

extern "C" void kernel_launch(void* const* d_in, const int* in_sizes, int n_in,
                              void* d_out, int out_size, void* d_ws,
                              size_t ws_size, hipStream_t stream) {
  const float* x = (const float*)d_in[0];
  const float* Wq = (const float*)d_in[1];
  const float* Wk = (const float*)d_in[2];
  const float* Wv = (const float*)d_in[3];
  const float* Wo = (const float*)d_in[4];
  const float* bo = (const float*)d_in[5];
  float* out = (float*)d_out;

  char* ws = (char*)d_ws;
  u16* xb = (u16*)(ws);                              // 16 MiB
  u16* wqkv = (u16*)(ws + (size_t)(16 << 20));       // 24 MiB
  u16* wob = (u16*)(ws + (size_t)(40 << 20));        // 8 MiB
  u16* qkv = (u16*)(ws + (size_t)(48 << 20));        // 48 MiB: Q | K | vt
  u16* vt = qkv + (size_t)2 * 8388608;               // vt in the V slot
  u16* attn = xb;                                    // reuse after GEMMs

  // fp32 -> bf16 (one fused launch)
  conv_all<<<24576, 256, 0, stream>>>(x, Wq, Wk, Wv, Wo, xb, wqkv, wob);

  // Q,K (fused RoPE) + V^T: 256x128 tiles, 768 blocks = 3 exact CU-rounds
  gemm_qkv<<<dim3(48, 16), 512, 0, stream>>>(xb, wqkv, qkv, vt);
  // flash attention
  attn_kernel<<<dim3(16, 32), 256, 0, stream>>>(qkv, vt, attn);
  // out = attn @ wob^T + bo: 256x128 tiles, 256 blocks = 1 exact CU-round
  gemm_out<<<dim3(16, 16), 512, 0, stream>>>(attn, wob, out, bo);
}